// Round 4
// baseline (580.539 us; speedup 1.0000x reference)
//
#include <hip/hip_runtime.h>

#define NN 50000
#define NE 800000
#define NB 196          // ceil(NN/256) node buckets of 256 nodes
#define SUBS 8          // append sub-streams per bucket (~XCD-local)
#define CAP8 1024       // capacity per (bucket,sub): mean 510, +23 sigma
// D = 128 features, HEADS=8, HID=16

// ---------------- zero int buffer ----------------
__global__ __launch_bounds__(256) void zero_int_kernel(int* __restrict__ p, int n) {
    int i = blockIdx.x * 256 + threadIdx.x;
    if (i < n) p[i] = 0;
}

// ---------------- GEMM: Y[nrows,128] = X[nrows,128] @ W[128,128] + bias ----------------
__global__ __launch_bounds__(256) void gemm128_kernel(
    const float* __restrict__ X, const float* __restrict__ W,
    const float* __restrict__ bias, float* __restrict__ Y, int nrows)
{
    __shared__ float wl[32 * 128];
    __shared__ float hl[64 * 132];
    const int t = threadIdx.x;
    const int lane = t & 63;
    const int wv = t >> 6;
    const int row0 = blockIdx.x * 64;

    {
        const float4* X4 = (const float4*)X;
        #pragma unroll
        for (int i = 0; i < 8; i++) {
            int idx = t + i * 256;
            int rr = idx >> 5, kk = idx & 31;
            int row = row0 + rr;
            float4 v = make_float4(0.f, 0.f, 0.f, 0.f);
            if (row < nrows) v = X4[(long)row * 32 + kk];
            *(float4*)&hl[rr * 132 + kk * 4] = v;
        }
    }

    float acc0[16], acc1[16];
    #pragma unroll
    for (int r = 0; r < 16; r++) { acc0[r] = 0.f; acc1[r] = 0.f; }

    for (int k0 = 0; k0 < 128; k0 += 32) {
        __syncthreads();
        {
            const float4* W4 = (const float4*)(W + k0 * 128);
            float4* wl4 = (float4*)wl;
            #pragma unroll
            for (int i = 0; i < 4; i++) wl4[t + i * 256] = W4[t + i * 256];
        }
        __syncthreads();
        #pragma unroll
        for (int kg = 0; kg < 8; kg++) {
            const int k = kg * 4;
            float w0[4], w1[4];
            #pragma unroll
            for (int j = 0; j < 4; j++) {
                w0[j] = wl[(k + j) * 128 + lane];
                w1[j] = wl[(k + j) * 128 + lane + 64];
            }
            const int rbase = wv * 16;
            #pragma unroll
            for (int r = 0; r < 16; r++) {
                float4 hv = *(const float4*)&hl[(rbase + r) * 132 + k0 + k];
                acc0[r] = fmaf(hv.x, w0[0], acc0[r]);
                acc0[r] = fmaf(hv.y, w0[1], acc0[r]);
                acc0[r] = fmaf(hv.z, w0[2], acc0[r]);
                acc0[r] = fmaf(hv.w, w0[3], acc0[r]);
                acc1[r] = fmaf(hv.x, w1[0], acc1[r]);
                acc1[r] = fmaf(hv.y, w1[1], acc1[r]);
                acc1[r] = fmaf(hv.z, w1[2], acc1[r]);
                acc1[r] = fmaf(hv.w, w1[3], acc1[r]);
            }
        }
    }

    const float b0 = bias[lane], b1 = bias[lane + 64];
    #pragma unroll
    for (int r = 0; r < 16; r++) {
        int row = row0 + wv * 16 + r;
        if (row < nrows) {
            Y[(long)row * 128 + lane]      = acc0[r] + b0;
            Y[(long)row * 128 + lane + 64] = acc1[r] + b1;
        }
    }
}

// ---------------- bin: append packed (dloc<<16|src) into (bucket, blockIdx&7) streams ----------------
__global__ __launch_bounds__(256) void bin_kernel(
    const int* __restrict__ src1, const int* __restrict__ dst1,
    const int* __restrict__ src2, const int* __restrict__ dst2,
    int* __restrict__ cnt, unsigned int* __restrict__ bin)
{
    int gid = blockIdx.x * 256 + threadIdx.x;
    if (gid >= NE) return;
    int sub = blockIdx.x & (SUBS - 1);
    {
        int d = dst1[gid], s = src1[gid];
        int ci = ((d >> 8) << 3) | sub;                      // graph 0
        int slot = atomicAdd(&cnt[ci], 1);
        if (slot < CAP8)
            bin[(size_t)ci * CAP8 + slot] = ((unsigned)(d & 255) << 16) | (unsigned)s;
    }
    {
        int d = dst2[gid], s = src2[gid];
        int ci = (NB * SUBS) + (((d >> 8) << 3) | sub);      // graph 1
        int slot = atomicAdd(&cnt[ci], 1);
        if (slot < CAP8)
            bin[(size_t)ci * CAP8 + slot] = ((unsigned)(d & 255) << 16) | (unsigned)s;
    }
}

// ---------------- bucket scan: exclusive scan of bucket totals per graph (1 block) ----------------
__global__ __launch_bounds__(256) void bucket_scan_kernel(
    const int* __restrict__ cnt, int* __restrict__ bbase)
{
    __shared__ int sc[256];
    const int t = threadIdx.x;
    for (int g = 0; g < 2; g++) {
        int tot = 0;
        if (t < NB) {
            const int* c = cnt + (g * NB + t) * SUBS;
            #pragma unroll
            for (int s = 0; s < SUBS; s++) tot += c[s];
        }
        sc[t] = tot;
        __syncthreads();
        for (int off = 1; off < 256; off <<= 1) {
            int x = (t >= off) ? sc[t - off] : 0;
            __syncthreads();
            sc[t] += x;
            __syncthreads();
        }
        if (t < NB) bbase[g * NB + t] = sc[t] - tot;         // exclusive
        __syncthreads();
    }
}

// ---------------- bucket sort: LDS counting sort per bucket, coalesced csr flush ----------------
__global__ __launch_bounds__(256) void bucket_sort_kernel(
    const int* __restrict__ cnt, const unsigned int* __restrict__ bin,
    const int* __restrict__ bbase,
    unsigned short* __restrict__ csr1, int* __restrict__ start1, int* __restrict__ deg1,
    unsigned short* __restrict__ csr2, int* __restrict__ start2, int* __restrict__ deg2)
{
    __shared__ int lcnt[256];
    __shared__ int sc[256];
    __shared__ int oat[256];
    __shared__ unsigned short outb[SUBS * CAP8];
    const int t = threadIdx.x;
    const int g = (blockIdx.x >= NB) ? 1 : 0;
    const int b = blockIdx.x - g * NB;
    unsigned short* csr = g ? csr2 : csr1;
    int* start = g ? start2 : start1;
    int* deg   = g ? deg2 : deg1;

    const int cbase = (g * NB + b) * SUBS;
    int cs[SUBS];
    #pragma unroll
    for (int s = 0; s < SUBS; s++) cs[s] = min(cnt[cbase + s], CAP8);

    lcnt[t] = 0;
    __syncthreads();
    // histogram local node ids
    #pragma unroll
    for (int s = 0; s < SUBS; s++) {
        const unsigned int* bp = bin + (size_t)(cbase + s) * CAP8;
        for (int i = t; i < cs[s]; i += 256)
            atomicAdd(&lcnt[bp[i] >> 16], 1);
    }
    __syncthreads();
    // inclusive scan of 256 counters
    sc[t] = lcnt[t];
    __syncthreads();
    for (int off = 1; off < 256; off <<= 1) {
        int x = (t >= off) ? sc[t - off] : 0;
        __syncthreads();
        sc[t] += x;
        __syncthreads();
    }
    const int ex = sc[t] - lcnt[t];
    const int total = sc[255];
    oat[t] = ex;
    __syncthreads();
    // place into LDS at sorted positions
    #pragma unroll
    for (int s = 0; s < SUBS; s++) {
        const unsigned int* bp = bin + (size_t)(cbase + s) * CAP8;
        for (int i = t; i < cs[s]; i += 256) {
            unsigned v = bp[i];
            int slot = atomicAdd(&oat[v >> 16], 1);
            outb[slot] = (unsigned short)(v & 0xFFFFu);
        }
    }
    __syncthreads();
    // coalesced flush of the bucket's contiguous csr region
    const int gbase = bbase[g * NB + b];
    for (int i = t; i < total; i += 256) csr[gbase + i] = outb[i];
    // per-node start/deg
    int nd = b * 256 + t;
    if (nd < NN) { start[nd] = gbase + ex; deg[nd] = lcnt[t]; }
}

// ---------------- gather: agg[v] = sum_{e: dst=v} hf[src_e] * norm[src_e] ----------------
__global__ __launch_bounds__(256) void gather_kernel(
    const float* __restrict__ hf, const unsigned short* __restrict__ csr,
    const int* __restrict__ start, const int* __restrict__ deg,
    const float* __restrict__ norm, float* __restrict__ agg)
{
    int wave = (blockIdx.x * 256 + threadIdx.x) >> 6;   // node id
    int lane = threadIdx.x & 63;
    if (wave >= NN) return;
    int st = start[wave];
    int dg = deg[wave];
    const float2* hf2 = (const float2*)hf;
    float2 acc = make_float2(0.f, 0.f);
    int i = 0;
    for (; i + 4 <= dg; i += 4) {
        int s0 = csr[st + i], s1 = csr[st + i + 1], s2 = csr[st + i + 2], s3 = csr[st + i + 3];
        float n0 = norm[s0], n1 = norm[s1], n2 = norm[s2], n3 = norm[s3];
        float2 v0 = hf2[(long)s0 * 64 + lane];
        float2 v1 = hf2[(long)s1 * 64 + lane];
        float2 v2 = hf2[(long)s2 * 64 + lane];
        float2 v3 = hf2[(long)s3 * 64 + lane];
        acc.x = fmaf(v0.x, n0, acc.x); acc.y = fmaf(v0.y, n0, acc.y);
        acc.x = fmaf(v1.x, n1, acc.x); acc.y = fmaf(v1.y, n1, acc.y);
        acc.x = fmaf(v2.x, n2, acc.x); acc.y = fmaf(v2.y, n2, acc.y);
        acc.x = fmaf(v3.x, n3, acc.x); acc.y = fmaf(v3.y, n3, acc.y);
    }
    for (; i < dg; i++) {
        int s = csr[st + i];
        float nv = norm[s];
        float2 v = hf2[(long)s * 64 + lane];
        acc.x = fmaf(v.x, nv, acc.x); acc.y = fmaf(v.y, nv, acc.y);
    }
    ((float2*)agg)[(long)wave * 64 + lane] = acc;
}

// ---------------- attention combine (flat "reshape" space), in-place into agg1 ----------------
__global__ __launch_bounds__(256) void attention_kernel(
    const float* __restrict__ hf, float* __restrict__ agg1,
    const float* __restrict__ agg2, const float* __restrict__ norm1,
    const float* __restrict__ norm2, const float* __restrict__ al,
    const float* __restrict__ ar)
{
    int gid = blockIdx.x * 256 + threadIdx.x;   // = m*4 + j
    int m = gid >> 2;
    int j = gid & 3;
    if (m >= 8 * NN) return;
    int n = m >> 3;
    int head = m / NN;
    float n1 = norm1[n], n2v = norm2[n];
    float4 f  = ((const float4*)hf)[gid];
    float4 g1 = ((const float4*)agg1)[gid];
    float4 g2 = ((const float4*)agg2)[gid];
    g1.x *= n1; g1.y *= n1; g1.z *= n1; g1.w *= n1;
    g2.x *= n2v; g2.y *= n2v; g2.z *= n2v; g2.w *= n2v;
    float4 av = ((const float4*)al)[head * 4 + j];
    float4 rv = ((const float4*)ar)[head * 4 + j];
    float s_ai = f.x * av.x + f.y * av.y + f.z * av.z + f.w * av.w;
    float s1 = g1.x * rv.x + g1.y * rv.y + g1.z * rv.z + g1.w * rv.w;
    float s2 = g2.x * rv.x + g2.y * rv.y + g2.z * rv.z + g2.w * rv.w;
    s_ai += __shfl_xor(s_ai, 1); s_ai += __shfl_xor(s_ai, 2);
    s1   += __shfl_xor(s1, 1);   s1   += __shfl_xor(s1, 2);
    s2   += __shfl_xor(s2, 1);   s2   += __shfl_xor(s2, 2);
    float x1 = s_ai + s1; x1 = x1 > 0.f ? x1 : 0.2f * x1;
    float x2 = s_ai + s2; x2 = x2 > 0.f ? x2 : 0.2f * x2;
    float e1 = fminf(expf(x1), 10.f);
    float e2 = fminf(expf(x2), 10.f);
    float inv = 1.f / (e1 + e2);
    float w1 = e1 * inv, w2 = e2 * inv;
    float4 o;
    o.x = w1 * g1.x + w2 * g2.x;
    o.y = w1 * g1.y + w2 * g2.y;
    o.z = w1 * g1.z + w2 * g2.z;
    o.w = w1 * g1.w + w2 * g2.w;
    ((float4*)agg1)[gid] = o;
}

extern "C" void kernel_launch(void* const* d_in, const int* in_sizes, int n_in,
                              void* d_out, int out_size, void* d_ws, size_t ws_size,
                              hipStream_t stream)
{
    const float* h     = (const float*)d_in[0];
    const int*   src1  = (const int*)  d_in[1];
    const int*   dst1  = (const int*)  d_in[2];
    const int*   src2  = (const int*)  d_in[3];
    const int*   dst2  = (const int*)  d_in[4];
    const float* norm1 = (const float*)d_in[5];
    const float* norm2 = (const float*)d_in[6];
    const float* W_lin = (const float*)d_in[7];
    const float* b_lin = (const float*)d_in[8];
    const float* al    = (const float*)d_in[9];
    const float* ar    = (const float*)d_in[10];
    const float* W_fc  = (const float*)d_in[11];
    const float* b_fc  = (const float*)d_in[12];
    float* out = (float*)d_out;

    // workspace layout
    float* hf    = (float*)d_ws;                          // 25.6 MB
    float* agg1  = hf   + (size_t)NN * 128;               // 25.6 MB
    float* agg2  = agg1 + (size_t)NN * 128;               // 25.6 MB
    // bin buffer aliases agg2: bin is dead before gather writes agg2
    unsigned int* bin = (unsigned int*)agg2;              // 2*NB*8*CAP8 u32 = 12.8 MB
    unsigned short* csr1 = (unsigned short*)(agg2 + (size_t)NN * 128);  // NE u16
    unsigned short* csr2 = csr1 + NE;                                   // NE u16
    int* cnt    = (int*)(csr2 + NE);                      // 2*NB*8 = 3136 ints
    int* bbase  = cnt + 2 * NB * SUBS;                    // 392 ints
    int* start1 = bbase + 2 * NB;
    int* start2 = start1 + NN;
    int* deg1   = start2 + NN;
    int* deg2   = deg1 + NN;

    // zero the append counters
    zero_int_kernel<<<(2 * NB * SUBS + 255) / 256, 256, 0, stream>>>(cnt, 2 * NB * SUBS);

    // hf = h @ W_lin + b_lin
    gemm128_kernel<<<(NN + 63) / 64, 256, 0, stream>>>(h, W_lin, b_lin, hf, NN);

    // CSR build: bin -> bucket scan -> per-bucket LDS counting sort
    bin_kernel<<<NE / 256, 256, 0, stream>>>(src1, dst1, src2, dst2, cnt, bin);
    bucket_scan_kernel<<<1, 256, 0, stream>>>(cnt, bbase);
    bucket_sort_kernel<<<2 * NB, 256, 0, stream>>>(cnt, bin, bbase,
                                                   csr1, start1, deg1,
                                                   csr2, start2, deg2);

    // atomic-free gather per graph
    gather_kernel<<<(NN * 64 + 255) / 256, 256, 0, stream>>>(hf, csr1, start1, deg1, norm1, agg1);
    gather_kernel<<<(NN * 64 + 255) / 256, 256, 0, stream>>>(hf, csr2, start2, deg2, norm2, agg2);

    // attention combine (in-place into agg1)
    attention_kernel<<<8 * NN * 4 / 256, 256, 0, stream>>>(hf, agg1, agg2, norm1, norm2, al, ar);

    // out = agg1 @ W_fc + b_fc
    gemm128_kernel<<<(NN + 63) / 64, 256, 0, stream>>>(agg1, W_fc, b_fc, out, NN);
}

// Round 5
// 372.429 us; speedup vs baseline: 1.5588x; 1.5588x over previous
//
#include <hip/hip_runtime.h>

#define NN 50000
#define NE 800000
#define NB 196          // ceil(NN/256) node buckets of 256 nodes
#define NBLK 512        // edge chunks
#define CHUNK 1563      // ceil(NE/NBLK)
#define MAXB 6144       // max edges per bucket (mean 4081; 6144 = +32 sigma)
// D = 128 features, HEADS=8, HID=16

// ---------------- GEMM: Y[nrows,128] = X[nrows,128] @ W[128,128] + bias ----------------
__global__ __launch_bounds__(256) void gemm128_kernel(
    const float* __restrict__ X, const float* __restrict__ W,
    const float* __restrict__ bias, float* __restrict__ Y, int nrows)
{
    __shared__ float wl[32 * 128];
    __shared__ float hl[64 * 132];
    const int t = threadIdx.x;
    const int lane = t & 63;
    const int wv = t >> 6;
    const int row0 = blockIdx.x * 64;

    {
        const float4* X4 = (const float4*)X;
        #pragma unroll
        for (int i = 0; i < 8; i++) {
            int idx = t + i * 256;
            int rr = idx >> 5, kk = idx & 31;
            int row = row0 + rr;
            float4 v = make_float4(0.f, 0.f, 0.f, 0.f);
            if (row < nrows) v = X4[(long)row * 32 + kk];
            *(float4*)&hl[rr * 132 + kk * 4] = v;
        }
    }

    float acc0[16], acc1[16];
    #pragma unroll
    for (int r = 0; r < 16; r++) { acc0[r] = 0.f; acc1[r] = 0.f; }

    for (int k0 = 0; k0 < 128; k0 += 32) {
        __syncthreads();
        {
            const float4* W4 = (const float4*)(W + k0 * 128);
            float4* wl4 = (float4*)wl;
            #pragma unroll
            for (int i = 0; i < 4; i++) wl4[t + i * 256] = W4[t + i * 256];
        }
        __syncthreads();
        #pragma unroll
        for (int kg = 0; kg < 8; kg++) {
            const int k = kg * 4;
            float w0[4], w1[4];
            #pragma unroll
            for (int j = 0; j < 4; j++) {
                w0[j] = wl[(k + j) * 128 + lane];
                w1[j] = wl[(k + j) * 128 + lane + 64];
            }
            const int rbase = wv * 16;
            #pragma unroll
            for (int r = 0; r < 16; r++) {
                float4 hv = *(const float4*)&hl[(rbase + r) * 132 + k0 + k];
                acc0[r] = fmaf(hv.x, w0[0], acc0[r]);
                acc0[r] = fmaf(hv.y, w0[1], acc0[r]);
                acc0[r] = fmaf(hv.z, w0[2], acc0[r]);
                acc0[r] = fmaf(hv.w, w0[3], acc0[r]);
                acc1[r] = fmaf(hv.x, w1[0], acc1[r]);
                acc1[r] = fmaf(hv.y, w1[1], acc1[r]);
                acc1[r] = fmaf(hv.z, w1[2], acc1[r]);
                acc1[r] = fmaf(hv.w, w1[3], acc1[r]);
            }
        }
    }

    const float b0 = bias[lane], b1 = bias[lane + 64];
    #pragma unroll
    for (int r = 0; r < 16; r++) {
        int row = row0 + wv * 16 + r;
        if (row < nrows) {
            Y[(long)row * 128 + lane]      = acc0[r] + b0;
            Y[(long)row * 128 + lane + 64] = acc1[r] + b1;
        }
    }
}

// ---------------- phase A: per-chunk LDS histogram over (graph,bucket) ----------------
__global__ __launch_bounds__(256) void histA_kernel(
    const int* __restrict__ dst1, const int* __restrict__ dst2, int* __restrict__ histG)
{
    __shared__ int h[2 * NB];
    const int t = threadIdx.x, blk = blockIdx.x;
    for (int i = t; i < 2 * NB; i += 256) h[i] = 0;
    __syncthreads();
    const int base = blk * CHUNK;
    const int lim = min(CHUNK, NE - base);
    for (int i = t; i < lim; i += 256) {
        atomicAdd(&h[dst1[base + i] >> 8], 1);
        atomicAdd(&h[NB + (dst2[base + i] >> 8)], 1);
    }
    __syncthreads();
    for (int i = t; i < 2 * NB; i += 256)
        histG[(size_t)i * NBLK + blk] = h[i];
}

// ---------------- phase B1: exclusive scan of each gb row across blocks ----------------
__global__ __launch_bounds__(512) void scanB1_kernel(int* __restrict__ histG, int* __restrict__ btot)
{
    __shared__ int s[NBLK];
    const int t = threadIdx.x, row = blockIdx.x;
    int v = histG[(size_t)row * NBLK + t];
    s[t] = v;
    __syncthreads();
    for (int off = 1; off < NBLK; off <<= 1) {
        int x = (t >= off) ? s[t - off] : 0;
        __syncthreads();
        s[t] += x;
        __syncthreads();
    }
    histG[(size_t)row * NBLK + t] = s[t] - v;   // exclusive intra-bucket offset
    if (t == NBLK - 1) btot[row] = s[t];
}

// ---------------- phase B2: exclusive scan of bucket totals per graph ----------------
__global__ __launch_bounds__(256) void scanB2_kernel(const int* __restrict__ btot, int* __restrict__ bbase)
{
    __shared__ int sc[256];
    const int t = threadIdx.x;
    for (int g = 0; g < 2; g++) {
        int v = (t < NB) ? btot[g * NB + t] : 0;
        sc[t] = v;
        __syncthreads();
        for (int off = 1; off < 256; off <<= 1) {
            int x = (t >= off) ? sc[t - off] : 0;
            __syncthreads();
            sc[t] += x;
            __syncthreads();
        }
        if (t < NB) bbase[g * NB + t] = sc[t] - v;
        __syncthreads();
    }
}

// ---------------- phase C: deterministic scatter into bucket-contiguous bins ----------------
__global__ __launch_bounds__(256) void scatterC_kernel(
    const int* __restrict__ src1, const int* __restrict__ dst1,
    const int* __restrict__ src2, const int* __restrict__ dst2,
    const int* __restrict__ histG, const int* __restrict__ bbase,
    unsigned int* __restrict__ bin1, unsigned int* __restrict__ bin2)
{
    __shared__ int pos[2 * NB];
    const int t = threadIdx.x, blk = blockIdx.x;
    for (int i = t; i < 2 * NB; i += 256)
        pos[i] = bbase[i] + histG[(size_t)i * NBLK + blk];
    __syncthreads();
    const int base = blk * CHUNK;
    const int lim = min(CHUNK, NE - base);
    for (int i = t; i < lim; i += 256) {
        int d = dst1[base + i], s = src1[base + i];
        int slot = atomicAdd(&pos[d >> 8], 1);
        bin1[slot] = ((unsigned)(d & 255) << 16) | (unsigned)s;
        d = dst2[base + i]; s = src2[base + i];
        slot = atomicAdd(&pos[NB + (d >> 8)], 1);
        bin2[slot] = ((unsigned)(d & 255) << 16) | (unsigned)s;
    }
}

// ---------------- bucket sort: LDS counting sort per bucket, coalesced csr flush ----------------
__global__ __launch_bounds__(256) void bucket_sort_kernel(
    const unsigned int* __restrict__ bin1, const unsigned int* __restrict__ bin2,
    const int* __restrict__ bbase, const int* __restrict__ btot,
    unsigned short* __restrict__ csr1, int* __restrict__ start1, int* __restrict__ deg1,
    unsigned short* __restrict__ csr2, int* __restrict__ start2, int* __restrict__ deg2)
{
    __shared__ int lcnt[256];
    __shared__ int sc[256];
    __shared__ int oat[256];
    __shared__ unsigned short outb[MAXB];
    const int t = threadIdx.x;
    const int g = (blockIdx.x >= NB) ? 1 : 0;
    const int b = blockIdx.x - g * NB;
    const unsigned int* bin = g ? bin2 : bin1;
    unsigned short* csr = g ? csr2 : csr1;
    int* start = g ? start2 : start1;
    int* deg   = g ? deg2 : deg1;

    const int base = bbase[g * NB + b];
    const int tot = min(btot[g * NB + b], MAXB);

    lcnt[t] = 0;
    __syncthreads();
    for (int i = t; i < tot; i += 256) atomicAdd(&lcnt[bin[base + i] >> 16], 1);
    __syncthreads();
    sc[t] = lcnt[t];
    __syncthreads();
    for (int off = 1; off < 256; off <<= 1) {
        int x = (t >= off) ? sc[t - off] : 0;
        __syncthreads();
        sc[t] += x;
        __syncthreads();
    }
    const int ex = sc[t] - lcnt[t];
    oat[t] = ex;
    __syncthreads();
    for (int i = t; i < tot; i += 256) {
        unsigned v = bin[base + i];
        int slot = atomicAdd(&oat[v >> 16], 1);
        outb[slot] = (unsigned short)(v & 0xFFFFu);
    }
    __syncthreads();
    for (int i = t; i < tot; i += 256) csr[base + i] = outb[i];
    int nd = b * 256 + t;
    if (nd < NN) { start[nd] = base + ex; deg[nd] = lcnt[t]; }
}

// ---------------- gather: agg[v] = sum_{e: dst=v} hf[src_e] * norm[src_e] ----------------
__global__ __launch_bounds__(256) void gather_kernel(
    const float* __restrict__ hf, const unsigned short* __restrict__ csr,
    const int* __restrict__ start, const int* __restrict__ deg,
    const float* __restrict__ norm, float* __restrict__ agg)
{
    int wave = (blockIdx.x * 256 + threadIdx.x) >> 6;   // node id
    int lane = threadIdx.x & 63;
    if (wave >= NN) return;
    int st = start[wave];
    int dg = deg[wave];
    const float2* hf2 = (const float2*)hf;
    float2 acc = make_float2(0.f, 0.f);
    int i = 0;
    for (; i + 4 <= dg; i += 4) {
        int s0 = csr[st + i], s1 = csr[st + i + 1], s2 = csr[st + i + 2], s3 = csr[st + i + 3];
        float n0 = norm[s0], n1 = norm[s1], n2 = norm[s2], n3 = norm[s3];
        float2 v0 = hf2[(long)s0 * 64 + lane];
        float2 v1 = hf2[(long)s1 * 64 + lane];
        float2 v2 = hf2[(long)s2 * 64 + lane];
        float2 v3 = hf2[(long)s3 * 64 + lane];
        acc.x = fmaf(v0.x, n0, acc.x); acc.y = fmaf(v0.y, n0, acc.y);
        acc.x = fmaf(v1.x, n1, acc.x); acc.y = fmaf(v1.y, n1, acc.y);
        acc.x = fmaf(v2.x, n2, acc.x); acc.y = fmaf(v2.y, n2, acc.y);
        acc.x = fmaf(v3.x, n3, acc.x); acc.y = fmaf(v3.y, n3, acc.y);
    }
    for (; i < dg; i++) {
        int s = csr[st + i];
        float nv = norm[s];
        float2 v = hf2[(long)s * 64 + lane];
        acc.x = fmaf(v.x, nv, acc.x); acc.y = fmaf(v.y, nv, acc.y);
    }
    ((float2*)agg)[(long)wave * 64 + lane] = acc;
}

// ---------------- attention combine (flat "reshape" space), in-place into agg1 ----------------
__global__ __launch_bounds__(256) void attention_kernel(
    const float* __restrict__ hf, float* __restrict__ agg1,
    const float* __restrict__ agg2, const float* __restrict__ norm1,
    const float* __restrict__ norm2, const float* __restrict__ al,
    const float* __restrict__ ar)
{
    int gid = blockIdx.x * 256 + threadIdx.x;   // = m*4 + j
    int m = gid >> 2;
    int j = gid & 3;
    if (m >= 8 * NN) return;
    int n = m >> 3;
    int head = m / NN;
    float n1 = norm1[n], n2v = norm2[n];
    float4 f  = ((const float4*)hf)[gid];
    float4 g1 = ((const float4*)agg1)[gid];
    float4 g2 = ((const float4*)agg2)[gid];
    g1.x *= n1; g1.y *= n1; g1.z *= n1; g1.w *= n1;
    g2.x *= n2v; g2.y *= n2v; g2.z *= n2v; g2.w *= n2v;
    float4 av = ((const float4*)al)[head * 4 + j];
    float4 rv = ((const float4*)ar)[head * 4 + j];
    float s_ai = f.x * av.x + f.y * av.y + f.z * av.z + f.w * av.w;
    float s1 = g1.x * rv.x + g1.y * rv.y + g1.z * rv.z + g1.w * rv.w;
    float s2 = g2.x * rv.x + g2.y * rv.y + g2.z * rv.z + g2.w * rv.w;
    s_ai += __shfl_xor(s_ai, 1); s_ai += __shfl_xor(s_ai, 2);
    s1   += __shfl_xor(s1, 1);   s1   += __shfl_xor(s1, 2);
    s2   += __shfl_xor(s2, 1);   s2   += __shfl_xor(s2, 2);
    float x1 = s_ai + s1; x1 = x1 > 0.f ? x1 : 0.2f * x1;
    float x2 = s_ai + s2; x2 = x2 > 0.f ? x2 : 0.2f * x2;
    float e1 = fminf(expf(x1), 10.f);
    float e2 = fminf(expf(x2), 10.f);
    float inv = 1.f / (e1 + e2);
    float w1 = e1 * inv, w2 = e2 * inv;
    float4 o;
    o.x = w1 * g1.x + w2 * g2.x;
    o.y = w1 * g1.y + w2 * g2.y;
    o.z = w1 * g1.z + w2 * g2.z;
    o.w = w1 * g1.w + w2 * g2.w;
    ((float4*)agg1)[gid] = o;
}

extern "C" void kernel_launch(void* const* d_in, const int* in_sizes, int n_in,
                              void* d_out, int out_size, void* d_ws, size_t ws_size,
                              hipStream_t stream)
{
    const float* h     = (const float*)d_in[0];
    const int*   src1  = (const int*)  d_in[1];
    const int*   dst1  = (const int*)  d_in[2];
    const int*   src2  = (const int*)  d_in[3];
    const int*   dst2  = (const int*)  d_in[4];
    const float* norm1 = (const float*)d_in[5];
    const float* norm2 = (const float*)d_in[6];
    const float* W_lin = (const float*)d_in[7];
    const float* b_lin = (const float*)d_in[8];
    const float* al    = (const float*)d_in[9];
    const float* ar    = (const float*)d_in[10];
    const float* W_fc  = (const float*)d_in[11];
    const float* b_fc  = (const float*)d_in[12];
    float* out = (float*)d_out;

    // workspace layout
    float* hf    = (float*)d_ws;                          // 25.6 MB
    float* agg1  = hf   + (size_t)NN * 128;               // 25.6 MB
    float* agg2  = agg1 + (size_t)NN * 128;               // 25.6 MB
    // bin buffers alias agg2 (bin is fully consumed by bucket_sort before gather writes agg2)
    unsigned int* bin1 = (unsigned int*)agg2;             // NE u32 = 3.2 MB
    unsigned int* bin2 = bin1 + NE;                       // NE u32 = 3.2 MB
    unsigned short* csr1 = (unsigned short*)(agg2 + (size_t)NN * 128);  // NE u16
    unsigned short* csr2 = csr1 + NE;                                   // NE u16
    int* histG  = (int*)(csr2 + NE);                      // 2*NB*NBLK ints = 784 KB
    int* btot   = histG + 2 * NB * NBLK;                  // 392
    int* bbase  = btot + 2 * NB;                          // 392
    int* start1 = bbase + 2 * NB;
    int* start2 = start1 + NN;
    int* deg1   = start2 + NN;
    int* deg2   = deg1 + NN;

    // hf = h @ W_lin + b_lin
    gemm128_kernel<<<(NN + 63) / 64, 256, 0, stream>>>(h, W_lin, b_lin, hf, NN);

    // deterministic CSR build: hist -> intra scan -> bucket scan -> scatter -> per-bucket sort
    histA_kernel<<<NBLK, 256, 0, stream>>>(dst1, dst2, histG);
    scanB1_kernel<<<2 * NB, NBLK, 0, stream>>>(histG, btot);
    scanB2_kernel<<<1, 256, 0, stream>>>(btot, bbase);
    scatterC_kernel<<<NBLK, 256, 0, stream>>>(src1, dst1, src2, dst2, histG, bbase, bin1, bin2);
    bucket_sort_kernel<<<2 * NB, 256, 0, stream>>>(bin1, bin2, bbase, btot,
                                                   csr1, start1, deg1,
                                                   csr2, start2, deg2);

    // atomic-free gather per graph
    gather_kernel<<<(NN * 64 + 255) / 256, 256, 0, stream>>>(hf, csr1, start1, deg1, norm1, agg1);
    gather_kernel<<<(NN * 64 + 255) / 256, 256, 0, stream>>>(hf, csr2, start2, deg2, norm2, agg2);

    // attention combine (in-place into agg1)
    attention_kernel<<<8 * NN * 4 / 256, 256, 0, stream>>>(hf, agg1, agg2, norm1, norm2, al, ar);

    // out = agg1 @ W_fc + b_fc
    gemm128_kernel<<<(NN + 63) / 64, 256, 0, stream>>>(agg1, W_fc, b_fc, out, NN);
}

// Round 6
// 278.513 us; speedup vs baseline: 2.0844x; 1.3372x over previous
//
#include <hip/hip_runtime.h>

#define NN 50000
#define NE 800000
#define NB 196          // ceil(NN/256) node buckets of 256 nodes
#define NBLK 512        // edge chunks
#define CHUNK 1563      // ceil(NE/NBLK)
#define MAXB 6144       // max edges per bucket (mean 4081; +32 sigma)
// D = 128 features, HEADS=8, HID=16

typedef __bf16 bf16x8 __attribute__((ext_vector_type(8)));
typedef float  f32x4  __attribute__((ext_vector_type(4)));

__device__ __forceinline__ unsigned short f2bf(float x) {
    unsigned u = __float_as_uint(x);
    return (unsigned short)((u + 0x7FFFu + ((u >> 16) & 1u)) >> 16);   // RNE
}
__device__ __forceinline__ float bflo(unsigned u) { return __uint_as_float(u << 16); }
__device__ __forceinline__ float bfhi(unsigned u) { return __uint_as_float(u & 0xFFFF0000u); }

// ---------------- MFMA GEMM: Y[nrows,128] = X_f32[nrows,128] @ W_f32[128,128] + bias ----
// X split into bf16 hi+lo (2 MFMAs, fp32-grade X); W rounded to bf16 once.
// 256 thr = 4 waves; block = 64 rows; wave = 16 rows x 128 cols; 16x16x32 bf16 MFMA.
// Outputs: Y fp32 (nullable) and/or Ybf bf16 (nullable).
__global__ __launch_bounds__(256) void mfma_gemm_kernel(
    const float* __restrict__ X, const float* __restrict__ W,
    const float* __restrict__ bias, float* __restrict__ Y,
    unsigned short* __restrict__ Ybf, int nrows)
{
    __shared__ unsigned short Wt[128 * 136];   // W transposed k-major: Wt[n][k], 34.8 KB
    __shared__ unsigned short Xh[64 * 136];    // 17.4 KB (pad 136 -> 2-way LDS = free)
    __shared__ unsigned short Xl[64 * 136];    // 17.4 KB
    const int t = threadIdx.x;
    const int lane = t & 63;
    const int wv = t >> 6;
    const int row0 = blockIdx.x * 64;
    const int m16 = lane & 15;       // col-in-tile / row-in-A
    const int quad = lane >> 4;      // 0..3

    // stage W as bf16, transposed (k contiguous per n)
    for (int i = t; i < 128 * 128; i += 256) {
        int k = i >> 7, n = i & 127;
        Wt[n * 136 + k] = f2bf(W[i]);
    }
    // stage X rows as bf16 hi/lo
    {
        const float4* X4 = (const float4*)X;
        #pragma unroll
        for (int i = 0; i < 8; i++) {
            int idx = t + i * 256;              // 0..2047
            int rr = idx >> 5, kk = (idx & 31) * 4;
            int row = row0 + rr;
            float4 v = make_float4(0.f, 0.f, 0.f, 0.f);
            if (row < nrows) v = X4[(long)row * 32 + (idx & 31)];
            ushort4 h, l;
            h.x = f2bf(v.x); l.x = f2bf(v.x - bflo(h.x));
            h.y = f2bf(v.y); l.y = f2bf(v.y - bflo(h.y));
            h.z = f2bf(v.z); l.z = f2bf(v.z - bflo(h.z));
            h.w = f2bf(v.w); l.w = f2bf(v.w - bflo(h.w));
            *(ushort4*)&Xh[rr * 136 + kk] = h;
            *(ushort4*)&Xl[rr * 136 + kk] = l;
        }
    }
    __syncthreads();

    f32x4 acc[8];
    #pragma unroll
    for (int nt = 0; nt < 8; nt++) acc[nt] = (f32x4){0.f, 0.f, 0.f, 0.f};

    const int arow = wv * 16 + m16;            // A row within block tile
    #pragma unroll
    for (int kc = 0; kc < 4; kc++) {
        const int ko = kc * 32 + quad * 8;
        bf16x8 ah = *(const bf16x8*)&Xh[arow * 136 + ko];
        bf16x8 al = *(const bf16x8*)&Xl[arow * 136 + ko];
        #pragma unroll
        for (int nt = 0; nt < 8; nt++) {
            bf16x8 b = *(const bf16x8*)&Wt[(nt * 16 + m16) * 136 + ko];
            acc[nt] = __builtin_amdgcn_mfma_f32_16x16x32_bf16(ah, b, acc[nt], 0, 0, 0);
            acc[nt] = __builtin_amdgcn_mfma_f32_16x16x32_bf16(al, b, acc[nt], 0, 0, 0);
        }
    }

    // epilogue: D[row=quad*4+r][col=nt*16+m16]
    #pragma unroll
    for (int nt = 0; nt < 8; nt++) {
        const int col = nt * 16 + m16;
        const float bc = bias[col];
        #pragma unroll
        for (int r = 0; r < 4; r++) {
            int row = row0 + wv * 16 + quad * 4 + r;
            if (row < nrows) {
                float val = acc[nt][r] + bc;
                if (Y)   Y[(long)row * 128 + col] = val;
                if (Ybf) Ybf[(long)row * 128 + col] = f2bf(val);
            }
        }
    }
}

// ---------------- phase A: per-chunk LDS histogram over (graph,bucket) ----------------
__global__ __launch_bounds__(256) void histA_kernel(
    const int* __restrict__ dst1, const int* __restrict__ dst2, int* __restrict__ histG)
{
    __shared__ int h[2 * NB];
    const int t = threadIdx.x, blk = blockIdx.x;
    for (int i = t; i < 2 * NB; i += 256) h[i] = 0;
    __syncthreads();
    const int base = blk * CHUNK;
    const int lim = min(CHUNK, NE - base);
    for (int i = t; i < lim; i += 256) {
        atomicAdd(&h[dst1[base + i] >> 8], 1);
        atomicAdd(&h[NB + (dst2[base + i] >> 8)], 1);
    }
    __syncthreads();
    for (int i = t; i < 2 * NB; i += 256)
        histG[(size_t)i * NBLK + blk] = h[i];
}

// ---------------- phase B1: exclusive scan of each gb row across blocks ----------------
__global__ __launch_bounds__(512) void scanB1_kernel(int* __restrict__ histG, int* __restrict__ btot)
{
    __shared__ int s[NBLK];
    const int t = threadIdx.x, row = blockIdx.x;
    int v = histG[(size_t)row * NBLK + t];
    s[t] = v;
    __syncthreads();
    for (int off = 1; off < NBLK; off <<= 1) {
        int x = (t >= off) ? s[t - off] : 0;
        __syncthreads();
        s[t] += x;
        __syncthreads();
    }
    histG[(size_t)row * NBLK + t] = s[t] - v;
    if (t == NBLK - 1) btot[row] = s[t];
}

// ---------------- phase B2: exclusive scan of bucket totals per graph ----------------
__global__ __launch_bounds__(256) void scanB2_kernel(const int* __restrict__ btot, int* __restrict__ bbase)
{
    __shared__ int sc[256];
    const int t = threadIdx.x;
    for (int g = 0; g < 2; g++) {
        int v = (t < NB) ? btot[g * NB + t] : 0;
        sc[t] = v;
        __syncthreads();
        for (int off = 1; off < 256; off <<= 1) {
            int x = (t >= off) ? sc[t - off] : 0;
            __syncthreads();
            sc[t] += x;
            __syncthreads();
        }
        if (t < NB) bbase[g * NB + t] = sc[t] - v;
        __syncthreads();
    }
}

// ---------------- phase C: deterministic scatter into bucket-contiguous bins ----------------
__global__ __launch_bounds__(256) void scatterC_kernel(
    const int* __restrict__ src1, const int* __restrict__ dst1,
    const int* __restrict__ src2, const int* __restrict__ dst2,
    const int* __restrict__ histG, const int* __restrict__ bbase,
    unsigned int* __restrict__ bin1, unsigned int* __restrict__ bin2)
{
    __shared__ int pos[2 * NB];
    const int t = threadIdx.x, blk = blockIdx.x;
    for (int i = t; i < 2 * NB; i += 256)
        pos[i] = bbase[i] + histG[(size_t)i * NBLK + blk];
    __syncthreads();
    const int base = blk * CHUNK;
    const int lim = min(CHUNK, NE - base);
    for (int i = t; i < lim; i += 256) {
        int d = dst1[base + i], s = src1[base + i];
        int slot = atomicAdd(&pos[d >> 8], 1);
        bin1[slot] = ((unsigned)(d & 255) << 16) | (unsigned)s;
        d = dst2[base + i]; s = src2[base + i];
        slot = atomicAdd(&pos[NB + (d >> 8)], 1);
        bin2[slot] = ((unsigned)(d & 255) << 16) | (unsigned)s;
    }
}

// ---------------- bucket sort: LDS counting sort per bucket, coalesced csr flush ----------------
__global__ __launch_bounds__(256) void bucket_sort_kernel(
    const unsigned int* __restrict__ bin1, const unsigned int* __restrict__ bin2,
    const int* __restrict__ bbase, const int* __restrict__ btot,
    unsigned short* __restrict__ csr1, int* __restrict__ start1, int* __restrict__ deg1,
    unsigned short* __restrict__ csr2, int* __restrict__ start2, int* __restrict__ deg2)
{
    __shared__ int lcnt[256];
    __shared__ int sc[256];
    __shared__ int oat[256];
    __shared__ unsigned short outb[MAXB];
    const int t = threadIdx.x;
    const int g = (blockIdx.x >= NB) ? 1 : 0;
    const int b = blockIdx.x - g * NB;
    const unsigned int* bin = g ? bin2 : bin1;
    unsigned short* csr = g ? csr2 : csr1;
    int* start = g ? start2 : start1;
    int* deg   = g ? deg2 : deg1;

    const int base = bbase[g * NB + b];
    const int tot = min(btot[g * NB + b], MAXB);

    lcnt[t] = 0;
    __syncthreads();
    for (int i = t; i < tot; i += 256) atomicAdd(&lcnt[bin[base + i] >> 16], 1);
    __syncthreads();
    sc[t] = lcnt[t];
    __syncthreads();
    for (int off = 1; off < 256; off <<= 1) {
        int x = (t >= off) ? sc[t - off] : 0;
        __syncthreads();
        sc[t] += x;
        __syncthreads();
    }
    const int ex = sc[t] - lcnt[t];
    oat[t] = ex;
    __syncthreads();
    for (int i = t; i < tot; i += 256) {
        unsigned v = bin[base + i];
        int slot = atomicAdd(&oat[v >> 16], 1);
        outb[slot] = (unsigned short)(v & 0xFFFFu);
    }
    __syncthreads();
    for (int i = t; i < tot; i += 256) csr[base + i] = outb[i];
    int nd = b * 256 + t;
    if (nd < NN) { start[nd] = base + ex; deg[nd] = lcnt[t]; }
}

// ---------------- gather (bf16 features): agg[v] = sum hfb[src]*norm[src] ----------------
// one wave per node; lane owns one u32 = 2 bf16 cols; 256 B per row, coalesced
__global__ __launch_bounds__(256) void gather_kernel(
    const unsigned int* __restrict__ hfb, const unsigned short* __restrict__ csr,
    const int* __restrict__ start, const int* __restrict__ deg,
    const float* __restrict__ norm, float* __restrict__ agg)
{
    int node = (blockIdx.x * 256 + threadIdx.x) >> 6;
    int lane = threadIdx.x & 63;
    if (node >= NN) return;
    int st = start[node];
    int dg = deg[node];
    float2 acc = make_float2(0.f, 0.f);
    int i = 0;
    for (; i + 4 <= dg; i += 4) {
        int s0 = csr[st + i], s1 = csr[st + i + 1], s2 = csr[st + i + 2], s3 = csr[st + i + 3];
        float n0 = norm[s0], n1 = norm[s1], n2 = norm[s2], n3 = norm[s3];
        unsigned u0 = hfb[(long)s0 * 64 + lane];
        unsigned u1 = hfb[(long)s1 * 64 + lane];
        unsigned u2 = hfb[(long)s2 * 64 + lane];
        unsigned u3 = hfb[(long)s3 * 64 + lane];
        acc.x = fmaf(bflo(u0), n0, acc.x); acc.y = fmaf(bfhi(u0), n0, acc.y);
        acc.x = fmaf(bflo(u1), n1, acc.x); acc.y = fmaf(bfhi(u1), n1, acc.y);
        acc.x = fmaf(bflo(u2), n2, acc.x); acc.y = fmaf(bfhi(u2), n2, acc.y);
        acc.x = fmaf(bflo(u3), n3, acc.x); acc.y = fmaf(bfhi(u3), n3, acc.y);
    }
    for (; i < dg; i++) {
        int s = csr[st + i];
        float nv = norm[s];
        unsigned u = hfb[(long)s * 64 + lane];
        acc.x = fmaf(bflo(u), nv, acc.x); acc.y = fmaf(bfhi(u), nv, acc.y);
    }
    ((float2*)agg)[(long)node * 64 + lane] = acc;
}

// ---------------- attention combine (flat space, bf16 hf), in-place into agg1 ----------------
__global__ __launch_bounds__(256) void attention_kernel(
    const unsigned int* __restrict__ hfb, float* __restrict__ agg1,
    const float* __restrict__ agg2, const float* __restrict__ norm1,
    const float* __restrict__ norm2, const float* __restrict__ al,
    const float* __restrict__ ar)
{
    int gid = blockIdx.x * 256 + threadIdx.x;   // = m*4 + j
    int m = gid >> 2;
    int j = gid & 3;
    if (m >= 8 * NN) return;
    int n = m >> 3;
    int head = m / NN;
    float n1 = norm1[n], n2v = norm2[n];
    uint2 u = ((const uint2*)hfb)[gid];
    float4 f = make_float4(bflo(u.x), bfhi(u.x), bflo(u.y), bfhi(u.y));
    float4 g1 = ((const float4*)agg1)[gid];
    float4 g2 = ((const float4*)agg2)[gid];
    g1.x *= n1; g1.y *= n1; g1.z *= n1; g1.w *= n1;
    g2.x *= n2v; g2.y *= n2v; g2.z *= n2v; g2.w *= n2v;
    float4 av = ((const float4*)al)[head * 4 + j];
    float4 rv = ((const float4*)ar)[head * 4 + j];
    float s_ai = f.x * av.x + f.y * av.y + f.z * av.z + f.w * av.w;
    float s1 = g1.x * rv.x + g1.y * rv.y + g1.z * rv.z + g1.w * rv.w;
    float s2 = g2.x * rv.x + g2.y * rv.y + g2.z * rv.z + g2.w * rv.w;
    s_ai += __shfl_xor(s_ai, 1); s_ai += __shfl_xor(s_ai, 2);
    s1   += __shfl_xor(s1, 1);   s1   += __shfl_xor(s1, 2);
    s2   += __shfl_xor(s2, 1);   s2   += __shfl_xor(s2, 2);
    float x1 = s_ai + s1; x1 = x1 > 0.f ? x1 : 0.2f * x1;
    float x2 = s_ai + s2; x2 = x2 > 0.f ? x2 : 0.2f * x2;
    float e1 = fminf(expf(x1), 10.f);
    float e2 = fminf(expf(x2), 10.f);
    float inv = 1.f / (e1 + e2);
    float w1 = e1 * inv, w2 = e2 * inv;
    float4 o;
    o.x = w1 * g1.x + w2 * g2.x;
    o.y = w1 * g1.y + w2 * g2.y;
    o.z = w1 * g1.z + w2 * g2.z;
    o.w = w1 * g1.w + w2 * g2.w;
    ((float4*)agg1)[gid] = o;
}

extern "C" void kernel_launch(void* const* d_in, const int* in_sizes, int n_in,
                              void* d_out, int out_size, void* d_ws, size_t ws_size,
                              hipStream_t stream)
{
    const float* h     = (const float*)d_in[0];
    const int*   src1  = (const int*)  d_in[1];
    const int*   dst1  = (const int*)  d_in[2];
    const int*   src2  = (const int*)  d_in[3];
    const int*   dst2  = (const int*)  d_in[4];
    const float* norm1 = (const float*)d_in[5];
    const float* norm2 = (const float*)d_in[6];
    const float* W_lin = (const float*)d_in[7];
    const float* b_lin = (const float*)d_in[8];
    const float* al    = (const float*)d_in[9];
    const float* ar    = (const float*)d_in[10];
    const float* W_fc  = (const float*)d_in[11];
    const float* b_fc  = (const float*)d_in[12];
    float* out = (float*)d_out;

    // workspace layout
    float* agg1 = (float*)d_ws;                           // 25.6 MB
    float* agg2 = agg1 + (size_t)NN * 128;                // 25.6 MB
    // bins alias agg2 (fully consumed by bucket_sort before gather writes agg2)
    unsigned int* bin1 = (unsigned int*)agg2;             // NE u32
    unsigned int* bin2 = bin1 + NE;                       // NE u32
    unsigned short* hfb  = (unsigned short*)(agg2 + (size_t)NN * 128);  // NN*128 bf16 = 12.8 MB
    unsigned short* csr1 = hfb + (size_t)NN * 128;        // NE u16
    unsigned short* csr2 = csr1 + NE;                     // NE u16
    int* histG  = (int*)(csr2 + NE);                      // 2*NB*NBLK ints
    int* btot   = histG + 2 * NB * NBLK;
    int* bbase  = btot + 2 * NB;
    int* start1 = bbase + 2 * NB;
    int* start2 = start1 + NN;
    int* deg1   = start2 + NN;
    int* deg2   = deg1 + NN;

    // hfb = bf16(h @ W_lin + b_lin)   (fp32 copy never materialized)
    mfma_gemm_kernel<<<(NN + 63) / 64, 256, 0, stream>>>(h, W_lin, b_lin, nullptr, hfb, NN);

    // deterministic CSR build
    histA_kernel<<<NBLK, 256, 0, stream>>>(dst1, dst2, histG);
    scanB1_kernel<<<2 * NB, NBLK, 0, stream>>>(histG, btot);
    scanB2_kernel<<<1, 256, 0, stream>>>(btot, bbase);
    scatterC_kernel<<<NBLK, 256, 0, stream>>>(src1, dst1, src2, dst2, histG, bbase, bin1, bin2);
    bucket_sort_kernel<<<2 * NB, 256, 0, stream>>>(bin1, bin2, bbase, btot,
                                                   csr1, start1, deg1,
                                                   csr2, start2, deg2);

    // atomic-free gathers (bf16 feature reads, fp32 accumulate)
    gather_kernel<<<(NN * 64 + 255) / 256, 256, 0, stream>>>((const unsigned int*)hfb, csr1, start1, deg1, norm1, agg1);
    gather_kernel<<<(NN * 64 + 255) / 256, 256, 0, stream>>>((const unsigned int*)hfb, csr2, start2, deg2, norm2, agg2);

    // attention combine (in-place into agg1)
    attention_kernel<<<8 * NN * 4 / 256, 256, 0, stream>>>((const unsigned int*)hfb, agg1, agg2,
                                                           norm1, norm2, al, ar);

    // out = agg1 @ W_fc + b_fc
    mfma_gemm_kernel<<<(NN + 63) / 64, 256, 0, stream>>>(agg1, W_fc, b_fc, out, nullptr, NN);
}

// Round 7
// 262.147 us; speedup vs baseline: 2.2146x; 1.0624x over previous
//
#include <hip/hip_runtime.h>

#define NN 50000
#define NE 800000
#define NB 196          // ceil(NN/256) node buckets of 256 nodes
#define NBLK 512        // edge chunks
#define CHUNK 1563      // ceil(NE/NBLK)
#define MAXB 6144       // max edges per bucket (mean 4081; +32 sigma)
// D = 128 features, HEADS=8, HID=16

typedef __bf16 bf16x8 __attribute__((ext_vector_type(8)));
typedef float  f32x4  __attribute__((ext_vector_type(4)));

__device__ __forceinline__ unsigned short f2bf(float x) {
    unsigned u = __float_as_uint(x);
    return (unsigned short)((u + 0x7FFFu + ((u >> 16) & 1u)) >> 16);   // RNE
}
__device__ __forceinline__ float bflo(unsigned u) { return __uint_as_float(u << 16); }
__device__ __forceinline__ float bfhi(unsigned u) { return __uint_as_float(u & 0xFFFF0000u); }

// ---------------- W pre-convert: Wt[n][k] = bf16(W[k][n]), k-major, once per launch ----
__global__ __launch_bounds__(256) void convert_w_kernel(
    const float* __restrict__ Wa, const float* __restrict__ Wb,
    unsigned short* __restrict__ Wta, unsigned short* __restrict__ Wtb)
{
    __shared__ float ls[128 * 132];            // pad 132 (16B-aligned rows)
    const float* W = blockIdx.x ? Wb : Wa;
    unsigned short* Wt = blockIdx.x ? Wtb : Wta;
    const int t = threadIdx.x;
    // coalesced load of W[k][n] into ls[k*132+n]
    for (int i = t; i < 128 * 32; i += 256) {
        int k = i >> 5, n4 = i & 31;
        *(float4*)&ls[k * 132 + n4 * 4] = ((const float4*)W)[i];
    }
    __syncthreads();
    // coalesced bf16 write of transpose
    for (int j = t; j < 128 * 128; j += 256) {
        int n = j >> 7, k = j & 127;
        Wt[j] = f2bf(ls[k * 132 + n]);
    }
}

// ---------------- MFMA GEMM: Y[nrows,128] = X_f32[nrows,128] @ W[128,128] + bias ------
// Wt pre-converted bf16 k-major. W staged in LDS (32 KB) with 16B-granule XOR swizzle.
// X loaded per-lane directly from global, split hi/lo bf16 in registers (2 MFMAs).
// 256 thr = 4 waves; block = 64 rows; 16x16x32 bf16 MFMA.
__global__ __launch_bounds__(256) void mfma_gemm_kernel(
    const float* __restrict__ X, const unsigned short* __restrict__ Wt,
    const float* __restrict__ bias, float* __restrict__ Y,
    unsigned short* __restrict__ Ybf, int nrows)
{
    __shared__ unsigned short Wl[128 * 128];   // 32 KB, granule-swizzled
    const int t = threadIdx.x;
    const int lane = t & 63;
    const int wv = t >> 6;
    const int row0 = blockIdx.x * 64;
    const int m16 = lane & 15;       // col-in-tile / A-row
    const int quad = lane >> 4;      // 0..3

    // stage Wt -> LDS, swizzling 16B granules: granule g of row n stored at g^(n&15)
    {
        const uint4* Wg = (const uint4*)Wt;
        #pragma unroll
        for (int i = 0; i < 8; i++) {
            int gi = t + i * 256;                  // 0..2047
            int n = gi >> 4, g = gi & 15;
            uint4 v = Wg[gi];
            *(uint4*)&Wl[n * 128 + (((g ^ (n & 15)) << 3))] = v;
        }
    }

    // preload this lane's A granules straight from global (fragments partition the tile)
    const int arow = row0 + wv * 16 + m16;
    const bool valid = (arow < nrows);
    const float4* X4 = (const float4*)X;
    float4 xr[8];
    #pragma unroll
    for (int kc = 0; kc < 4; kc++) {
        if (valid) {
            int gidx = arow * 32 + kc * 8 + quad * 2;
            xr[kc * 2]     = X4[gidx];
            xr[kc * 2 + 1] = X4[gidx + 1];
        } else {
            xr[kc * 2] = xr[kc * 2 + 1] = make_float4(0.f, 0.f, 0.f, 0.f);
        }
    }
    __syncthreads();

    f32x4 acc[8];
    #pragma unroll
    for (int nt = 0; nt < 8; nt++) acc[nt] = (f32x4){0.f, 0.f, 0.f, 0.f};

    #pragma unroll
    for (int kc = 0; kc < 4; kc++) {
        union { unsigned short u[8]; bf16x8 v; } ah, al;
        float f[8] = { xr[kc*2].x, xr[kc*2].y, xr[kc*2].z, xr[kc*2].w,
                       xr[kc*2+1].x, xr[kc*2+1].y, xr[kc*2+1].z, xr[kc*2+1].w };
        #pragma unroll
        for (int j = 0; j < 8; j++) {
            unsigned u = __float_as_uint(f[j]);
            ah.u[j] = (unsigned short)(u >> 16);                    // hi = truncate
            al.u[j] = f2bf(f[j] - __uint_as_float(u & 0xFFFF0000u)); // lo = RNE residual
        }
        const int sgbase = (kc * 4 + quad);
        #pragma unroll
        for (int nt = 0; nt < 8; nt++) {
            const int n = nt * 16 + m16;
            bf16x8 b = *(const bf16x8*)&Wl[n * 128 + ((sgbase ^ m16) << 3)];
            acc[nt] = __builtin_amdgcn_mfma_f32_16x16x32_bf16(ah.v, b, acc[nt], 0, 0, 0);
            acc[nt] = __builtin_amdgcn_mfma_f32_16x16x32_bf16(al.v, b, acc[nt], 0, 0, 0);
        }
    }

    // epilogue: D[row=quad*4+r][col=nt*16+m16]
    #pragma unroll
    for (int nt = 0; nt < 8; nt++) {
        const int col = nt * 16 + m16;
        const float bc = bias[col];
        #pragma unroll
        for (int r = 0; r < 4; r++) {
            int row = row0 + wv * 16 + quad * 4 + r;
            if (row < nrows) {
                float val = acc[nt][r] + bc;
                if (Y)   Y[(long)row * 128 + col] = val;
                if (Ybf) Ybf[(long)row * 128 + col] = f2bf(val);
            }
        }
    }
}

// ---------------- phase A: per-chunk LDS histogram over (graph,bucket) ----------------
__global__ __launch_bounds__(256) void histA_kernel(
    const int* __restrict__ dst1, const int* __restrict__ dst2, int* __restrict__ histG)
{
    __shared__ int h[2 * NB];
    const int t = threadIdx.x, blk = blockIdx.x;
    for (int i = t; i < 2 * NB; i += 256) h[i] = 0;
    __syncthreads();
    const int base = blk * CHUNK;
    const int lim = min(CHUNK, NE - base);
    for (int i = t; i < lim; i += 256) {
        atomicAdd(&h[dst1[base + i] >> 8], 1);
        atomicAdd(&h[NB + (dst2[base + i] >> 8)], 1);
    }
    __syncthreads();
    for (int i = t; i < 2 * NB; i += 256)
        histG[(size_t)i * NBLK + blk] = h[i];
}

// ---------------- phase B1: exclusive scan of each gb row across blocks ----------------
__global__ __launch_bounds__(512) void scanB1_kernel(int* __restrict__ histG, int* __restrict__ btot)
{
    __shared__ int s[NBLK];
    const int t = threadIdx.x, row = blockIdx.x;
    int v = histG[(size_t)row * NBLK + t];
    s[t] = v;
    __syncthreads();
    for (int off = 1; off < NBLK; off <<= 1) {
        int x = (t >= off) ? s[t - off] : 0;
        __syncthreads();
        s[t] += x;
        __syncthreads();
    }
    histG[(size_t)row * NBLK + t] = s[t] - v;
    if (t == NBLK - 1) btot[row] = s[t];
}

// ---------------- phase B2: exclusive scan of bucket totals per graph ----------------
__global__ __launch_bounds__(256) void scanB2_kernel(const int* __restrict__ btot, int* __restrict__ bbase)
{
    __shared__ int sc[256];
    const int t = threadIdx.x;
    for (int g = 0; g < 2; g++) {
        int v = (t < NB) ? btot[g * NB + t] : 0;
        sc[t] = v;
        __syncthreads();
        for (int off = 1; off < 256; off <<= 1) {
            int x = (t >= off) ? sc[t - off] : 0;
            __syncthreads();
            sc[t] += x;
            __syncthreads();
        }
        if (t < NB) bbase[g * NB + t] = sc[t] - v;
        __syncthreads();
    }
}

// ---------------- phase C: deterministic scatter into bucket-contiguous bins ----------------
__global__ __launch_bounds__(256) void scatterC_kernel(
    const int* __restrict__ src1, const int* __restrict__ dst1,
    const int* __restrict__ src2, const int* __restrict__ dst2,
    const int* __restrict__ histG, const int* __restrict__ bbase,
    unsigned int* __restrict__ bin1, unsigned int* __restrict__ bin2)
{
    __shared__ int pos[2 * NB];
    const int t = threadIdx.x, blk = blockIdx.x;
    for (int i = t; i < 2 * NB; i += 256)
        pos[i] = bbase[i] + histG[(size_t)i * NBLK + blk];
    __syncthreads();
    const int base = blk * CHUNK;
    const int lim = min(CHUNK, NE - base);
    for (int i = t; i < lim; i += 256) {
        int d = dst1[base + i], s = src1[base + i];
        int slot = atomicAdd(&pos[d >> 8], 1);
        bin1[slot] = ((unsigned)(d & 255) << 16) | (unsigned)s;
        d = dst2[base + i]; s = src2[base + i];
        slot = atomicAdd(&pos[NB + (d >> 8)], 1);
        bin2[slot] = ((unsigned)(d & 255) << 16) | (unsigned)s;
    }
}

// ---------------- bucket sort: LDS counting sort per bucket, coalesced csr flush ----------------
__global__ __launch_bounds__(256) void bucket_sort_kernel(
    const unsigned int* __restrict__ bin1, const unsigned int* __restrict__ bin2,
    const int* __restrict__ bbase, const int* __restrict__ btot,
    unsigned short* __restrict__ csr1, int* __restrict__ start1, int* __restrict__ deg1,
    unsigned short* __restrict__ csr2, int* __restrict__ start2, int* __restrict__ deg2)
{
    __shared__ int lcnt[256];
    __shared__ int sc[256];
    __shared__ int oat[256];
    __shared__ unsigned short outb[MAXB];
    const int t = threadIdx.x;
    const int g = (blockIdx.x >= NB) ? 1 : 0;
    const int b = blockIdx.x - g * NB;
    const unsigned int* bin = g ? bin2 : bin1;
    unsigned short* csr = g ? csr2 : csr1;
    int* start = g ? start2 : start1;
    int* deg   = g ? deg2 : deg1;

    const int base = bbase[g * NB + b];
    const int tot = min(btot[g * NB + b], MAXB);

    lcnt[t] = 0;
    __syncthreads();
    for (int i = t; i < tot; i += 256) atomicAdd(&lcnt[bin[base + i] >> 16], 1);
    __syncthreads();
    sc[t] = lcnt[t];
    __syncthreads();
    for (int off = 1; off < 256; off <<= 1) {
        int x = (t >= off) ? sc[t - off] : 0;
        __syncthreads();
        sc[t] += x;
        __syncthreads();
    }
    const int ex = sc[t] - lcnt[t];
    oat[t] = ex;
    __syncthreads();
    for (int i = t; i < tot; i += 256) {
        unsigned v = bin[base + i];
        int slot = atomicAdd(&oat[v >> 16], 1);
        outb[slot] = (unsigned short)(v & 0xFFFFu);
    }
    __syncthreads();
    for (int i = t; i < tot; i += 256) csr[base + i] = outb[i];
    int nd = b * 256 + t;
    if (nd < NN) { start[nd] = base + ex; deg[nd] = lcnt[t]; }
}

// ---------------- fused gather (both graphs): agg[v] = sum hfb[src]*norm[src] ----------
__global__ __launch_bounds__(256) void gather_both_kernel(
    const unsigned int* __restrict__ hfb,
    const unsigned short* __restrict__ csr1, const int* __restrict__ start1,
    const int* __restrict__ deg1, const float* __restrict__ norm1, float* __restrict__ agg1,
    const unsigned short* __restrict__ csr2, const int* __restrict__ start2,
    const int* __restrict__ deg2, const float* __restrict__ norm2, float* __restrict__ agg2)
{
    int w = (blockIdx.x * 256 + threadIdx.x) >> 6;
    int lane = threadIdx.x & 63;
    if (w >= 2 * NN) return;
    const int g = (w >= NN);
    const int node = w - g * NN;
    const unsigned short* csr = g ? csr2 : csr1;
    const int* start = g ? start2 : start1;
    const int* deg   = g ? deg2 : deg1;
    const float* norm = g ? norm2 : norm1;
    float* agg = g ? agg2 : agg1;

    int st = start[node];
    int dg = deg[node];
    float2 acc = make_float2(0.f, 0.f);
    int i = 0;
    for (; i + 4 <= dg; i += 4) {
        int s0 = csr[st + i], s1 = csr[st + i + 1], s2 = csr[st + i + 2], s3 = csr[st + i + 3];
        float n0 = norm[s0], n1 = norm[s1], n2 = norm[s2], n3 = norm[s3];
        unsigned u0 = hfb[(long)s0 * 64 + lane];
        unsigned u1 = hfb[(long)s1 * 64 + lane];
        unsigned u2 = hfb[(long)s2 * 64 + lane];
        unsigned u3 = hfb[(long)s3 * 64 + lane];
        acc.x = fmaf(bflo(u0), n0, acc.x); acc.y = fmaf(bfhi(u0), n0, acc.y);
        acc.x = fmaf(bflo(u1), n1, acc.x); acc.y = fmaf(bfhi(u1), n1, acc.y);
        acc.x = fmaf(bflo(u2), n2, acc.x); acc.y = fmaf(bfhi(u2), n2, acc.y);
        acc.x = fmaf(bflo(u3), n3, acc.x); acc.y = fmaf(bfhi(u3), n3, acc.y);
    }
    for (; i < dg; i++) {
        int s = csr[st + i];
        float nv = norm[s];
        unsigned u = hfb[(long)s * 64 + lane];
        acc.x = fmaf(bflo(u), nv, acc.x); acc.y = fmaf(bfhi(u), nv, acc.y);
    }
    ((float2*)agg)[(long)node * 64 + lane] = acc;
}

// ---------------- attention combine (flat space, bf16 hf), in-place into agg1 ----------------
__global__ __launch_bounds__(256) void attention_kernel(
    const unsigned int* __restrict__ hfb, float* __restrict__ agg1,
    const float* __restrict__ agg2, const float* __restrict__ norm1,
    const float* __restrict__ norm2, const float* __restrict__ al,
    const float* __restrict__ ar)
{
    int gid = blockIdx.x * 256 + threadIdx.x;   // = m*4 + j
    int m = gid >> 2;
    int j = gid & 3;
    if (m >= 8 * NN) return;
    int n = m >> 3;
    int head = m / NN;
    float n1 = norm1[n], n2v = norm2[n];
    uint2 u = ((const uint2*)hfb)[gid];
    float4 f = make_float4(bflo(u.x), bfhi(u.x), bflo(u.y), bfhi(u.y));
    float4 g1 = ((const float4*)agg1)[gid];
    float4 g2 = ((const float4*)agg2)[gid];
    g1.x *= n1; g1.y *= n1; g1.z *= n1; g1.w *= n1;
    g2.x *= n2v; g2.y *= n2v; g2.z *= n2v; g2.w *= n2v;
    float4 av = ((const float4*)al)[head * 4 + j];
    float4 rv = ((const float4*)ar)[head * 4 + j];
    float s_ai = f.x * av.x + f.y * av.y + f.z * av.z + f.w * av.w;
    float s1 = g1.x * rv.x + g1.y * rv.y + g1.z * rv.z + g1.w * rv.w;
    float s2 = g2.x * rv.x + g2.y * rv.y + g2.z * rv.z + g2.w * rv.w;
    s_ai += __shfl_xor(s_ai, 1); s_ai += __shfl_xor(s_ai, 2);
    s1   += __shfl_xor(s1, 1);   s1   += __shfl_xor(s1, 2);
    s2   += __shfl_xor(s2, 1);   s2   += __shfl_xor(s2, 2);
    float x1 = s_ai + s1; x1 = x1 > 0.f ? x1 : 0.2f * x1;
    float x2 = s_ai + s2; x2 = x2 > 0.f ? x2 : 0.2f * x2;
    float e1 = fminf(expf(x1), 10.f);
    float e2 = fminf(expf(x2), 10.f);
    float inv = 1.f / (e1 + e2);
    float w1 = e1 * inv, w2 = e2 * inv;
    float4 o;
    o.x = w1 * g1.x + w2 * g2.x;
    o.y = w1 * g1.y + w2 * g2.y;
    o.z = w1 * g1.z + w2 * g2.z;
    o.w = w1 * g1.w + w2 * g2.w;
    ((float4*)agg1)[gid] = o;
}

extern "C" void kernel_launch(void* const* d_in, const int* in_sizes, int n_in,
                              void* d_out, int out_size, void* d_ws, size_t ws_size,
                              hipStream_t stream)
{
    const float* h     = (const float*)d_in[0];
    const int*   src1  = (const int*)  d_in[1];
    const int*   dst1  = (const int*)  d_in[2];
    const int*   src2  = (const int*)  d_in[3];
    const int*   dst2  = (const int*)  d_in[4];
    const float* norm1 = (const float*)d_in[5];
    const float* norm2 = (const float*)d_in[6];
    const float* W_lin = (const float*)d_in[7];
    const float* b_lin = (const float*)d_in[8];
    const float* al    = (const float*)d_in[9];
    const float* ar    = (const float*)d_in[10];
    const float* W_fc  = (const float*)d_in[11];
    const float* b_fc  = (const float*)d_in[12];
    float* out = (float*)d_out;

    // workspace layout
    float* agg1 = (float*)d_ws;                           // 25.6 MB
    float* agg2 = agg1 + (size_t)NN * 128;                // 25.6 MB
    // bins alias agg2 (fully consumed by bucket_sort before gather writes agg2)
    unsigned int* bin1 = (unsigned int*)agg2;             // NE u32
    unsigned int* bin2 = bin1 + NE;                       // NE u32
    unsigned short* hfb  = (unsigned short*)(agg2 + (size_t)NN * 128);  // NN*128 bf16
    unsigned short* csr1 = hfb + (size_t)NN * 128;        // NE u16
    unsigned short* csr2 = csr1 + NE;                     // NE u16
    unsigned short* WtL  = csr2 + NE;                     // 16384 u16 (32 KB)
    unsigned short* WtF  = WtL + 128 * 128;               // 16384 u16
    int* histG  = (int*)(WtF + 128 * 128);                // 2*NB*NBLK ints
    int* btot   = histG + 2 * NB * NBLK;
    int* bbase  = btot + 2 * NB;
    int* start1 = bbase + 2 * NB;
    int* start2 = start1 + NN;
    int* deg1   = start2 + NN;
    int* deg2   = deg1 + NN;

    // pre-convert both weight matrices to bf16 k-major (once)
    convert_w_kernel<<<2, 256, 0, stream>>>(W_lin, W_fc, WtL, WtF);

    // hfb = bf16(h @ W_lin + b_lin)
    mfma_gemm_kernel<<<(NN + 63) / 64, 256, 0, stream>>>(h, WtL, b_lin, nullptr, hfb, NN);

    // deterministic CSR build
    histA_kernel<<<NBLK, 256, 0, stream>>>(dst1, dst2, histG);
    scanB1_kernel<<<2 * NB, NBLK, 0, stream>>>(histG, btot);
    scanB2_kernel<<<1, 256, 0, stream>>>(btot, bbase);
    scatterC_kernel<<<NBLK, 256, 0, stream>>>(src1, dst1, src2, dst2, histG, bbase, bin1, bin2);
    bucket_sort_kernel<<<2 * NB, 256, 0, stream>>>(bin1, bin2, bbase, btot,
                                                   csr1, start1, deg1,
                                                   csr2, start2, deg2);

    // fused atomic-free gathers (bf16 feature reads, fp32 accumulate)
    gather_both_kernel<<<(2 * NN * 64 + 255) / 256, 256, 0, stream>>>(
        (const unsigned int*)hfb,
        csr1, start1, deg1, norm1, agg1,
        csr2, start2, deg2, norm2, agg2);

    // attention combine (in-place into agg1)
    attention_kernel<<<8 * NN * 4 / 256, 256, 0, stream>>>((const unsigned int*)hfb, agg1, agg2,
                                                           norm1, norm2, al, ar);

    // out = agg1 @ W_fc + b_fc
    mfma_gemm_kernel<<<(NN + 63) / 64, 256, 0, stream>>>(agg1, WtF, b_fc, out, nullptr, NN);
}

// Round 8
// 229.284 us; speedup vs baseline: 2.5320x; 1.1433x over previous
//
#include <hip/hip_runtime.h>

#define NN 50000
#define NE 800000
#define NB 196          // ceil(NN/256) node buckets of 256 nodes
#define NBLK 512        // edge chunks
#define CHUNK 1563      // ceil(NE/NBLK)
#define MAXB 6144       // max edges per bucket (mean 4081; +32 sigma)
// D = 128 features, HEADS=8, HID=16

typedef __bf16 bf16x8 __attribute__((ext_vector_type(8)));
typedef float  f32x4  __attribute__((ext_vector_type(4)));

__device__ __forceinline__ unsigned short f2bf(float x) {
    unsigned u = __float_as_uint(x);
    return (unsigned short)((u + 0x7FFFu + ((u >> 16) & 1u)) >> 16);   // RNE
}
__device__ __forceinline__ float bflo(unsigned u) { return __uint_as_float(u << 16); }
__device__ __forceinline__ float bfhi(unsigned u) { return __uint_as_float(u & 0xFFFF0000u); }

// ---------------- W pre-convert: Wt[n][k] = bf16(W[k][n]), k-major, once per launch ----
__global__ __launch_bounds__(256) void convert_w_kernel(
    const float* __restrict__ Wa, const float* __restrict__ Wb,
    unsigned short* __restrict__ Wta, unsigned short* __restrict__ Wtb)
{
    __shared__ float ls[128 * 132];
    const float* W = blockIdx.x ? Wb : Wa;
    unsigned short* Wt = blockIdx.x ? Wtb : Wta;
    const int t = threadIdx.x;
    for (int i = t; i < 128 * 32; i += 256) {
        int k = i >> 5, n4 = i & 31;
        *(float4*)&ls[k * 132 + n4 * 4] = ((const float4*)W)[i];
    }
    __syncthreads();
    for (int j = t; j < 128 * 128; j += 256) {
        int n = j >> 7, k = j & 127;
        Wt[j] = f2bf(ls[k * 132 + n]);
    }
}

// ---------------- MFMA GEMM (fp32 in): Y = X @ W + bias, X hi/lo split (2 MFMAs) ------
__global__ __launch_bounds__(256) void mfma_gemm_kernel(
    const float* __restrict__ X, const unsigned short* __restrict__ Wt,
    const float* __restrict__ bias, float* __restrict__ Y,
    unsigned short* __restrict__ Ybf, int nrows)
{
    __shared__ unsigned short Wl[128 * 128];   // 32 KB, granule-swizzled
    const int t = threadIdx.x;
    const int lane = t & 63;
    const int wv = t >> 6;
    const int row0 = blockIdx.x * 64;
    const int m16 = lane & 15;
    const int quad = lane >> 4;

    {
        const uint4* Wg = (const uint4*)Wt;
        #pragma unroll
        for (int i = 0; i < 8; i++) {
            int gi = t + i * 256;
            int n = gi >> 4, g = gi & 15;
            uint4 v = Wg[gi];
            *(uint4*)&Wl[n * 128 + (((g ^ (n & 15)) << 3))] = v;
        }
    }

    const int arow = row0 + wv * 16 + m16;
    const bool valid = (arow < nrows);
    const float4* X4 = (const float4*)X;
    float4 xr[8];
    #pragma unroll
    for (int kc = 0; kc < 4; kc++) {
        if (valid) {
            int gidx = arow * 32 + kc * 8 + quad * 2;
            xr[kc * 2]     = X4[gidx];
            xr[kc * 2 + 1] = X4[gidx + 1];
        } else {
            xr[kc * 2] = xr[kc * 2 + 1] = make_float4(0.f, 0.f, 0.f, 0.f);
        }
    }
    __syncthreads();

    f32x4 acc[8];
    #pragma unroll
    for (int nt = 0; nt < 8; nt++) acc[nt] = (f32x4){0.f, 0.f, 0.f, 0.f};

    #pragma unroll
    for (int kc = 0; kc < 4; kc++) {
        union { unsigned short u[8]; bf16x8 v; } ah, al;
        float f[8] = { xr[kc*2].x, xr[kc*2].y, xr[kc*2].z, xr[kc*2].w,
                       xr[kc*2+1].x, xr[kc*2+1].y, xr[kc*2+1].z, xr[kc*2+1].w };
        #pragma unroll
        for (int j = 0; j < 8; j++) {
            unsigned u = __float_as_uint(f[j]);
            ah.u[j] = (unsigned short)(u >> 16);
            al.u[j] = f2bf(f[j] - __uint_as_float(u & 0xFFFF0000u));
        }
        const int sgbase = (kc * 4 + quad);
        #pragma unroll
        for (int nt = 0; nt < 8; nt++) {
            const int n = nt * 16 + m16;
            bf16x8 b = *(const bf16x8*)&Wl[n * 128 + ((sgbase ^ m16) << 3)];
            acc[nt] = __builtin_amdgcn_mfma_f32_16x16x32_bf16(ah.v, b, acc[nt], 0, 0, 0);
            acc[nt] = __builtin_amdgcn_mfma_f32_16x16x32_bf16(al.v, b, acc[nt], 0, 0, 0);
        }
    }

    #pragma unroll
    for (int nt = 0; nt < 8; nt++) {
        const int col = nt * 16 + m16;
        const float bc = bias[col];
        #pragma unroll
        for (int r = 0; r < 4; r++) {
            int row = row0 + wv * 16 + quad * 4 + r;
            if (row < nrows) {
                float val = acc[nt][r] + bc;
                if (Y)   Y[(long)row * 128 + col] = val;
                if (Ybf) Ybf[(long)row * 128 + col] = f2bf(val);
            }
        }
    }
}

// ---------------- MFMA GEMM (bf16 in): Y = Xbf @ W + bias (1 MFMA per tile) -----------
__global__ __launch_bounds__(256) void mfma_gemm_bf16_kernel(
    const unsigned short* __restrict__ Xbf, const unsigned short* __restrict__ Wt,
    const float* __restrict__ bias, float* __restrict__ Y, int nrows)
{
    __shared__ unsigned short Wl[128 * 128];
    const int t = threadIdx.x;
    const int lane = t & 63;
    const int wv = t >> 6;
    const int row0 = blockIdx.x * 64;
    const int m16 = lane & 15;
    const int quad = lane >> 4;

    {
        const uint4* Wg = (const uint4*)Wt;
        #pragma unroll
        for (int i = 0; i < 8; i++) {
            int gi = t + i * 256;
            int n = gi >> 4, g = gi & 15;
            uint4 v = Wg[gi];
            *(uint4*)&Wl[n * 128 + (((g ^ (n & 15)) << 3))] = v;
        }
    }

    const int arow = row0 + wv * 16 + m16;
    const bool valid = (arow < nrows);
    const uint4* X16 = (const uint4*)Xbf;   // 8 bf16 per uint4
    union { uint4 u; bf16x8 v; } xr[4];
    #pragma unroll
    for (int kc = 0; kc < 4; kc++) {
        if (valid) xr[kc].u = X16[arow * 16 + kc * 4 + quad];
        else       xr[kc].u = make_uint4(0, 0, 0, 0);
    }
    __syncthreads();

    f32x4 acc[8];
    #pragma unroll
    for (int nt = 0; nt < 8; nt++) acc[nt] = (f32x4){0.f, 0.f, 0.f, 0.f};

    #pragma unroll
    for (int kc = 0; kc < 4; kc++) {
        const int sgbase = (kc * 4 + quad);
        #pragma unroll
        for (int nt = 0; nt < 8; nt++) {
            const int n = nt * 16 + m16;
            bf16x8 b = *(const bf16x8*)&Wl[n * 128 + ((sgbase ^ m16) << 3)];
            acc[nt] = __builtin_amdgcn_mfma_f32_16x16x32_bf16(xr[kc].v, b, acc[nt], 0, 0, 0);
        }
    }

    #pragma unroll
    for (int nt = 0; nt < 8; nt++) {
        const int col = nt * 16 + m16;
        const float bc = bias[col];
        #pragma unroll
        for (int r = 0; r < 4; r++) {
            int row = row0 + wv * 16 + quad * 4 + r;
            if (row < nrows) Y[(long)row * 128 + col] = acc[nt][r] + bc;
        }
    }
}

// ---------------- phase A: per-chunk LDS histogram over (graph,bucket) ----------------
__global__ __launch_bounds__(256) void histA_kernel(
    const int* __restrict__ dst1, const int* __restrict__ dst2, int* __restrict__ histG)
{
    __shared__ int h[2 * NB];
    const int t = threadIdx.x, blk = blockIdx.x;
    for (int i = t; i < 2 * NB; i += 256) h[i] = 0;
    __syncthreads();
    const int base = blk * CHUNK;
    const int lim = min(CHUNK, NE - base);
    for (int i = t; i < lim; i += 256) {
        atomicAdd(&h[dst1[base + i] >> 8], 1);
        atomicAdd(&h[NB + (dst2[base + i] >> 8)], 1);
    }
    __syncthreads();
    for (int i = t; i < 2 * NB; i += 256)
        histG[(size_t)i * NBLK + blk] = h[i];
}

// ---------------- phase B1: exclusive scan of each gb row across blocks ----------------
__global__ __launch_bounds__(512) void scanB1_kernel(int* __restrict__ histG, int* __restrict__ btot)
{
    __shared__ int s[NBLK];
    const int t = threadIdx.x, row = blockIdx.x;
    int v = histG[(size_t)row * NBLK + t];
    s[t] = v;
    __syncthreads();
    for (int off = 1; off < NBLK; off <<= 1) {
        int x = (t >= off) ? s[t - off] : 0;
        __syncthreads();
        s[t] += x;
        __syncthreads();
    }
    histG[(size_t)row * NBLK + t] = s[t] - v;
    if (t == NBLK - 1) btot[row] = s[t];
}

// ---------------- phase B2: exclusive scan of bucket totals per graph ----------------
__global__ __launch_bounds__(256) void scanB2_kernel(const int* __restrict__ btot, int* __restrict__ bbase)
{
    __shared__ int sc[256];
    const int t = threadIdx.x;
    for (int g = 0; g < 2; g++) {
        int v = (t < NB) ? btot[g * NB + t] : 0;
        sc[t] = v;
        __syncthreads();
        for (int off = 1; off < 256; off <<= 1) {
            int x = (t >= off) ? sc[t - off] : 0;
            __syncthreads();
            sc[t] += x;
            __syncthreads();
        }
        if (t < NB) bbase[g * NB + t] = sc[t] - v;
        __syncthreads();
    }
}

// ---------------- phase C: deterministic scatter into bucket-contiguous bins ----------------
__global__ __launch_bounds__(256) void scatterC_kernel(
    const int* __restrict__ src1, const int* __restrict__ dst1,
    const int* __restrict__ src2, const int* __restrict__ dst2,
    const int* __restrict__ histG, const int* __restrict__ bbase,
    unsigned int* __restrict__ bin1, unsigned int* __restrict__ bin2)
{
    __shared__ int pos[2 * NB];
    const int t = threadIdx.x, blk = blockIdx.x;
    for (int i = t; i < 2 * NB; i += 256)
        pos[i] = bbase[i] + histG[(size_t)i * NBLK + blk];
    __syncthreads();
    const int base = blk * CHUNK;
    const int lim = min(CHUNK, NE - base);
    for (int i = t; i < lim; i += 256) {
        int d = dst1[base + i], s = src1[base + i];
        int slot = atomicAdd(&pos[d >> 8], 1);
        bin1[slot] = ((unsigned)(d & 255) << 16) | (unsigned)s;
        d = dst2[base + i]; s = src2[base + i];
        slot = atomicAdd(&pos[NB + (d >> 8)], 1);
        bin2[slot] = ((unsigned)(d & 255) << 16) | (unsigned)s;
    }
}

// ---------------- bucket sort: LDS counting sort per bucket, coalesced csr flush ----------------
__global__ __launch_bounds__(256) void bucket_sort_kernel(
    const unsigned int* __restrict__ bin1, const unsigned int* __restrict__ bin2,
    const int* __restrict__ bbase, const int* __restrict__ btot,
    unsigned short* __restrict__ csr1, int* __restrict__ start1, int* __restrict__ deg1,
    unsigned short* __restrict__ csr2, int* __restrict__ start2, int* __restrict__ deg2)
{
    __shared__ int lcnt[256];
    __shared__ int sc[256];
    __shared__ int oat[256];
    __shared__ unsigned short outb[MAXB];
    const int t = threadIdx.x;
    const int g = (blockIdx.x >= NB) ? 1 : 0;
    const int b = blockIdx.x - g * NB;
    const unsigned int* bin = g ? bin2 : bin1;
    unsigned short* csr = g ? csr2 : csr1;
    int* start = g ? start2 : start1;
    int* deg   = g ? deg2 : deg1;

    const int base = bbase[g * NB + b];
    const int tot = min(btot[g * NB + b], MAXB);

    lcnt[t] = 0;
    __syncthreads();
    for (int i = t; i < tot; i += 256) atomicAdd(&lcnt[bin[base + i] >> 16], 1);
    __syncthreads();
    sc[t] = lcnt[t];
    __syncthreads();
    for (int off = 1; off < 256; off <<= 1) {
        int x = (t >= off) ? sc[t - off] : 0;
        __syncthreads();
        sc[t] += x;
        __syncthreads();
    }
    const int ex = sc[t] - lcnt[t];
    oat[t] = ex;
    __syncthreads();
    for (int i = t; i < tot; i += 256) {
        unsigned v = bin[base + i];
        int slot = atomicAdd(&oat[v >> 16], 1);
        outb[slot] = (unsigned short)(v & 0xFFFFu);
    }
    __syncthreads();
    for (int i = t; i < tot; i += 256) csr[base + i] = outb[i];
    int nd = b * 256 + t;
    if (nd < NN) { start[nd] = base + ex; deg[nd] = lcnt[t]; }
}

// ---------------- fused gather + attention: one wave per node, both graphs -------------
// Accumulates h1,h2 in registers, applies the per-chunk attention combine, writes bf16.
__global__ __launch_bounds__(256) void gather_attn_kernel(
    const unsigned int* __restrict__ hfb,
    const unsigned short* __restrict__ csr1, const int* __restrict__ start1,
    const int* __restrict__ deg1, const float* __restrict__ norm1,
    const unsigned short* __restrict__ csr2, const int* __restrict__ start2,
    const int* __restrict__ deg2, const float* __restrict__ norm2,
    const float* __restrict__ al, const float* __restrict__ ar,
    unsigned int* __restrict__ outb)
{
    const int lane = threadIdx.x & 63;
    int node = (blockIdx.x * 256 + threadIdx.x) >> 6;
    if (node >= NN) return;
    node = __builtin_amdgcn_readfirstlane(node);   // wave-uniform -> SGPR

    float2 acc1 = make_float2(0.f, 0.f), acc2 = make_float2(0.f, 0.f);

    // graph 1
    {
        const int st = start1[node], dg = deg1[node];
        for (int base = 0; base < dg; base += 64) {
            const int nb = min(64, dg - base);
            int myc = (lane < nb) ? (int)csr1[st + base + lane] : 0;  // coalesced 128B/wave
            int j = 0;
            for (; j + 4 <= nb; j += 4) {
                int s0 = __builtin_amdgcn_readlane(myc, j);
                int s1 = __builtin_amdgcn_readlane(myc, j + 1);
                int s2 = __builtin_amdgcn_readlane(myc, j + 2);
                int s3 = __builtin_amdgcn_readlane(myc, j + 3);
                float n0 = norm1[s0], n1 = norm1[s1], n2 = norm1[s2], n3 = norm1[s3];
                unsigned u0 = hfb[(long)s0 * 64 + lane];
                unsigned u1 = hfb[(long)s1 * 64 + lane];
                unsigned u2 = hfb[(long)s2 * 64 + lane];
                unsigned u3 = hfb[(long)s3 * 64 + lane];
                acc1.x = fmaf(bflo(u0), n0, acc1.x); acc1.y = fmaf(bfhi(u0), n0, acc1.y);
                acc1.x = fmaf(bflo(u1), n1, acc1.x); acc1.y = fmaf(bfhi(u1), n1, acc1.y);
                acc1.x = fmaf(bflo(u2), n2, acc1.x); acc1.y = fmaf(bfhi(u2), n2, acc1.y);
                acc1.x = fmaf(bflo(u3), n3, acc1.x); acc1.y = fmaf(bfhi(u3), n3, acc1.y);
            }
            for (; j < nb; j++) {
                int s = __builtin_amdgcn_readlane(myc, j);
                float nv = norm1[s];
                unsigned u = hfb[(long)s * 64 + lane];
                acc1.x = fmaf(bflo(u), nv, acc1.x); acc1.y = fmaf(bfhi(u), nv, acc1.y);
            }
        }
    }
    // graph 2
    {
        const int st = start2[node], dg = deg2[node];
        for (int base = 0; base < dg; base += 64) {
            const int nb = min(64, dg - base);
            int myc = (lane < nb) ? (int)csr2[st + base + lane] : 0;
            int j = 0;
            for (; j + 4 <= nb; j += 4) {
                int s0 = __builtin_amdgcn_readlane(myc, j);
                int s1 = __builtin_amdgcn_readlane(myc, j + 1);
                int s2 = __builtin_amdgcn_readlane(myc, j + 2);
                int s3 = __builtin_amdgcn_readlane(myc, j + 3);
                float n0 = norm2[s0], n1 = norm2[s1], n2 = norm2[s2], n3 = norm2[s3];
                unsigned u0 = hfb[(long)s0 * 64 + lane];
                unsigned u1 = hfb[(long)s1 * 64 + lane];
                unsigned u2 = hfb[(long)s2 * 64 + lane];
                unsigned u3 = hfb[(long)s3 * 64 + lane];
                acc2.x = fmaf(bflo(u0), n0, acc2.x); acc2.y = fmaf(bfhi(u0), n0, acc2.y);
                acc2.x = fmaf(bflo(u1), n1, acc2.x); acc2.y = fmaf(bfhi(u1), n1, acc2.y);
                acc2.x = fmaf(bflo(u2), n2, acc2.x); acc2.y = fmaf(bfhi(u2), n2, acc2.y);
                acc2.x = fmaf(bflo(u3), n3, acc2.x); acc2.y = fmaf(bfhi(u3), n3, acc2.y);
            }
            for (; j < nb; j++) {
                int s = __builtin_amdgcn_readlane(myc, j);
                float nv = norm2[s];
                unsigned u = hfb[(long)s * 64 + lane];
                acc2.x = fmaf(bflo(u), nv, acc2.x); acc2.y = fmaf(bfhi(u), nv, acc2.y);
            }
        }
    }

    // h1 = acc1*norm1[node], h2 = acc2*norm2[node]
    const float nn1 = norm1[node], nn2 = norm2[node];
    acc1.x *= nn1; acc1.y *= nn1;
    acc2.x *= nn2; acc2.y *= nn2;

    // attention combine in flat-reshape space: lane owns cols {2*lane, 2*lane+1}
    // chunk cc = lane>>3 (16 cols = 8 lanes); m = node*8+cc; head = m/NN
    const int cc = lane >> 3;
    const int m = node * 8 + cc;
    const int head = m / NN;
    const int hid = (2 * lane) & 15;
    unsigned uf = hfb[(long)node * 64 + lane];
    const float fx = bflo(uf), fy = bfhi(uf);
    const float av0 = al[head * 16 + hid], av1 = al[head * 16 + hid + 1];
    const float rv0 = ar[head * 16 + hid], rv1 = ar[head * 16 + hid + 1];
    float s_ai = fx * av0 + fy * av1;
    float s1 = acc1.x * rv0 + acc1.y * rv1;
    float s2 = acc2.x * rv0 + acc2.y * rv1;
    // reduce over the 8-lane chunk group
    s_ai += __shfl_xor(s_ai, 1); s_ai += __shfl_xor(s_ai, 2); s_ai += __shfl_xor(s_ai, 4);
    s1   += __shfl_xor(s1, 1);   s1   += __shfl_xor(s1, 2);   s1   += __shfl_xor(s1, 4);
    s2   += __shfl_xor(s2, 1);   s2   += __shfl_xor(s2, 2);   s2   += __shfl_xor(s2, 4);
    float x1 = s_ai + s1; x1 = x1 > 0.f ? x1 : 0.2f * x1;
    float x2 = s_ai + s2; x2 = x2 > 0.f ? x2 : 0.2f * x2;
    float e1 = fminf(expf(x1), 10.f);
    float e2 = fminf(expf(x2), 10.f);
    float inv = 1.f / (e1 + e2);
    float w1 = e1 * inv, w2 = e2 * inv;
    float ox = w1 * acc1.x + w2 * acc2.x;
    float oy = w1 * acc1.y + w2 * acc2.y;
    outb[(long)node * 64 + lane] = (unsigned)f2bf(ox) | ((unsigned)f2bf(oy) << 16);
}

extern "C" void kernel_launch(void* const* d_in, const int* in_sizes, int n_in,
                              void* d_out, int out_size, void* d_ws, size_t ws_size,
                              hipStream_t stream)
{
    const float* h     = (const float*)d_in[0];
    const int*   src1  = (const int*)  d_in[1];
    const int*   dst1  = (const int*)  d_in[2];
    const int*   src2  = (const int*)  d_in[3];
    const int*   dst2  = (const int*)  d_in[4];
    const float* norm1 = (const float*)d_in[5];
    const float* norm2 = (const float*)d_in[6];
    const float* W_lin = (const float*)d_in[7];
    const float* b_lin = (const float*)d_in[8];
    const float* al    = (const float*)d_in[9];
    const float* ar    = (const float*)d_in[10];
    const float* W_fc  = (const float*)d_in[11];
    const float* b_fc  = (const float*)d_in[12];
    float* out = (float*)d_out;

    // workspace layout (no aliasing needed anymore)
    unsigned short* hfb  = (unsigned short*)d_ws;         // NN*128 bf16 = 12.8 MB
    unsigned short* outbf = hfb + (size_t)NN * 128;       // NN*128 bf16 = 12.8 MB
    unsigned int* bin1 = (unsigned int*)(outbf + (size_t)NN * 128);  // NE u32
    unsigned int* bin2 = bin1 + NE;                       // NE u32
    unsigned short* csr1 = (unsigned short*)(bin2 + NE);  // NE u16
    unsigned short* csr2 = csr1 + NE;                     // NE u16
    unsigned short* WtL  = csr2 + NE;                     // 16384 u16
    unsigned short* WtF  = WtL + 128 * 128;               // 16384 u16
    int* histG  = (int*)(WtF + 128 * 128);                // 2*NB*NBLK ints
    int* btot   = histG + 2 * NB * NBLK;
    int* bbase  = btot + 2 * NB;
    int* start1 = bbase + 2 * NB;
    int* start2 = start1 + NN;
    int* deg1   = start2 + NN;
    int* deg2   = deg1 + NN;

    // pre-convert both weight matrices to bf16 k-major (once)
    convert_w_kernel<<<2, 256, 0, stream>>>(W_lin, W_fc, WtL, WtF);

    // hfb = bf16(h @ W_lin + b_lin)
    mfma_gemm_kernel<<<(NN + 63) / 64, 256, 0, stream>>>(h, WtL, b_lin, nullptr, hfb, NN);

    // deterministic CSR build
    histA_kernel<<<NBLK, 256, 0, stream>>>(dst1, dst2, histG);
    scanB1_kernel<<<2 * NB, NBLK, 0, stream>>>(histG, btot);
    scanB2_kernel<<<1, 256, 0, stream>>>(btot, bbase);
    scatterC_kernel<<<NBLK, 256, 0, stream>>>(src1, dst1, src2, dst2, histG, bbase, bin1, bin2);
    bucket_sort_kernel<<<2 * NB, 256, 0, stream>>>(bin1, bin2, bbase, btot,
                                                   csr1, start1, deg1,
                                                   csr2, start2, deg2);

    // fused gather (both graphs) + attention combine -> bf16
    gather_attn_kernel<<<(NN * 64 + 255) / 256, 256, 0, stream>>>(
        (const unsigned int*)hfb,
        csr1, start1, deg1, norm1,
        csr2, start2, deg2, norm2,
        al, ar, (unsigned int*)outbf);

    // out = outbf @ W_fc + b_fc
    mfma_gemm_bf16_kernel<<<(NN + 63) / 64, 256, 0, stream>>>(outbf, WtF, b_fc, out, NN);
}

// Round 9
// 227.654 us; speedup vs baseline: 2.5501x; 1.0072x over previous
//
#include <hip/hip_runtime.h>

#define NN 50000
#define NE 800000
#define NB 196          // ceil(NN/256) node buckets of 256 nodes
#define NBLK 128        // edge chunks (128 -> ~32 edges/bucket/block = full L2 lines)
#define CHUNK 6250      // NE / NBLK exactly
#define MAXB 6144       // max edges per bucket (mean 4081; +32 sigma)
// D = 128 features, HEADS=8, HID=16

typedef __bf16 bf16x8 __attribute__((ext_vector_type(8)));
typedef float  f32x4  __attribute__((ext_vector_type(4)));

__device__ __forceinline__ unsigned short f2bf(float x) {
    unsigned u = __float_as_uint(x);
    return (unsigned short)((u + 0x7FFFu + ((u >> 16) & 1u)) >> 16);   // RNE
}
__device__ __forceinline__ float bflo(unsigned u) { return __uint_as_float(u << 16); }
__device__ __forceinline__ float bfhi(unsigned u) { return __uint_as_float(u & 0xFFFF0000u); }

// ---------------- W pre-convert: Wt[n][k] = bf16(W[k][n]), k-major, once per launch ----
__global__ __launch_bounds__(256) void convert_w_kernel(
    const float* __restrict__ Wa, const float* __restrict__ Wb,
    unsigned short* __restrict__ Wta, unsigned short* __restrict__ Wtb)
{
    __shared__ float ls[128 * 132];
    const float* W = blockIdx.x ? Wb : Wa;
    unsigned short* Wt = blockIdx.x ? Wtb : Wta;
    const int t = threadIdx.x;
    for (int i = t; i < 128 * 32; i += 256) {
        int k = i >> 5, n4 = i & 31;
        *(float4*)&ls[k * 132 + n4 * 4] = ((const float4*)W)[i];
    }
    __syncthreads();
    for (int j = t; j < 128 * 128; j += 256) {
        int n = j >> 7, k = j & 127;
        Wt[j] = f2bf(ls[k * 132 + n]);
    }
}

// ---------------- MFMA GEMM (fp32 in): Y = X @ W + bias, X hi/lo split (2 MFMAs) ------
__global__ __launch_bounds__(256) void mfma_gemm_kernel(
    const float* __restrict__ X, const unsigned short* __restrict__ Wt,
    const float* __restrict__ bias, float* __restrict__ Y,
    unsigned short* __restrict__ Ybf, int nrows)
{
    __shared__ unsigned short Wl[128 * 128];   // 32 KB, granule-swizzled
    const int t = threadIdx.x;
    const int lane = t & 63;
    const int wv = t >> 6;
    const int row0 = blockIdx.x * 64;
    const int m16 = lane & 15;
    const int quad = lane >> 4;

    {
        const uint4* Wg = (const uint4*)Wt;
        #pragma unroll
        for (int i = 0; i < 8; i++) {
            int gi = t + i * 256;
            int n = gi >> 4, g = gi & 15;
            uint4 v = Wg[gi];
            *(uint4*)&Wl[n * 128 + (((g ^ (n & 15)) << 3))] = v;
        }
    }

    const int arow = row0 + wv * 16 + m16;
    const bool valid = (arow < nrows);
    const float4* X4 = (const float4*)X;
    float4 xr[8];
    #pragma unroll
    for (int kc = 0; kc < 4; kc++) {
        if (valid) {
            int gidx = arow * 32 + kc * 8 + quad * 2;
            xr[kc * 2]     = X4[gidx];
            xr[kc * 2 + 1] = X4[gidx + 1];
        } else {
            xr[kc * 2] = xr[kc * 2 + 1] = make_float4(0.f, 0.f, 0.f, 0.f);
        }
    }
    __syncthreads();

    f32x4 acc[8];
    #pragma unroll
    for (int nt = 0; nt < 8; nt++) acc[nt] = (f32x4){0.f, 0.f, 0.f, 0.f};

    #pragma unroll
    for (int kc = 0; kc < 4; kc++) {
        union { unsigned short u[8]; bf16x8 v; } ah, al;
        float f[8] = { xr[kc*2].x, xr[kc*2].y, xr[kc*2].z, xr[kc*2].w,
                       xr[kc*2+1].x, xr[kc*2+1].y, xr[kc*2+1].z, xr[kc*2+1].w };
        #pragma unroll
        for (int j = 0; j < 8; j++) {
            unsigned u = __float_as_uint(f[j]);
            ah.u[j] = (unsigned short)(u >> 16);
            al.u[j] = f2bf(f[j] - __uint_as_float(u & 0xFFFF0000u));
        }
        const int sgbase = (kc * 4 + quad);
        #pragma unroll
        for (int nt = 0; nt < 8; nt++) {
            const int n = nt * 16 + m16;
            bf16x8 b = *(const bf16x8*)&Wl[n * 128 + ((sgbase ^ m16) << 3)];
            acc[nt] = __builtin_amdgcn_mfma_f32_16x16x32_bf16(ah.v, b, acc[nt], 0, 0, 0);
            acc[nt] = __builtin_amdgcn_mfma_f32_16x16x32_bf16(al.v, b, acc[nt], 0, 0, 0);
        }
    }

    #pragma unroll
    for (int nt = 0; nt < 8; nt++) {
        const int col = nt * 16 + m16;
        const float bc = bias[col];
        #pragma unroll
        for (int r = 0; r < 4; r++) {
            int row = row0 + wv * 16 + quad * 4 + r;
            if (row < nrows) {
                float val = acc[nt][r] + bc;
                if (Y)   Y[(long)row * 128 + col] = val;
                if (Ybf) Ybf[(long)row * 128 + col] = f2bf(val);
            }
        }
    }
}

// ---------------- MFMA GEMM (bf16 in): Y = Xbf @ W + bias (1 MFMA per tile) -----------
__global__ __launch_bounds__(256) void mfma_gemm_bf16_kernel(
    const unsigned short* __restrict__ Xbf, const unsigned short* __restrict__ Wt,
    const float* __restrict__ bias, float* __restrict__ Y, int nrows)
{
    __shared__ unsigned short Wl[128 * 128];
    const int t = threadIdx.x;
    const int lane = t & 63;
    const int wv = t >> 6;
    const int row0 = blockIdx.x * 64;
    const int m16 = lane & 15;
    const int quad = lane >> 4;

    {
        const uint4* Wg = (const uint4*)Wt;
        #pragma unroll
        for (int i = 0; i < 8; i++) {
            int gi = t + i * 256;
            int n = gi >> 4, g = gi & 15;
            uint4 v = Wg[gi];
            *(uint4*)&Wl[n * 128 + (((g ^ (n & 15)) << 3))] = v;
        }
    }

    const int arow = row0 + wv * 16 + m16;
    const bool valid = (arow < nrows);
    const uint4* X16 = (const uint4*)Xbf;
    union { uint4 u; bf16x8 v; } xr[4];
    #pragma unroll
    for (int kc = 0; kc < 4; kc++) {
        if (valid) xr[kc].u = X16[arow * 16 + kc * 4 + quad];
        else       xr[kc].u = make_uint4(0, 0, 0, 0);
    }
    __syncthreads();

    f32x4 acc[8];
    #pragma unroll
    for (int nt = 0; nt < 8; nt++) acc[nt] = (f32x4){0.f, 0.f, 0.f, 0.f};

    #pragma unroll
    for (int kc = 0; kc < 4; kc++) {
        const int sgbase = (kc * 4 + quad);
        #pragma unroll
        for (int nt = 0; nt < 8; nt++) {
            const int n = nt * 16 + m16;
            bf16x8 b = *(const bf16x8*)&Wl[n * 128 + ((sgbase ^ m16) << 3)];
            acc[nt] = __builtin_amdgcn_mfma_f32_16x16x32_bf16(xr[kc].v, b, acc[nt], 0, 0, 0);
        }
    }

    #pragma unroll
    for (int nt = 0; nt < 8; nt++) {
        const int col = nt * 16 + m16;
        const float bc = bias[col];
        #pragma unroll
        for (int r = 0; r < 4; r++) {
            int row = row0 + wv * 16 + quad * 4 + r;
            if (row < nrows) Y[(long)row * 128 + col] = acc[nt][r] + bc;
        }
    }
}

// ---------------- phase A: per-chunk LDS histogram over (graph,bucket) ----------------
__global__ __launch_bounds__(1024) void histA_kernel(
    const int* __restrict__ dst1, const int* __restrict__ dst2, int* __restrict__ histG)
{
    __shared__ int h[2 * NB];
    const int t = threadIdx.x, blk = blockIdx.x;
    for (int i = t; i < 2 * NB; i += 1024) h[i] = 0;
    __syncthreads();
    const int base = blk * CHUNK;
    for (int i = t; i < CHUNK; i += 1024) {
        atomicAdd(&h[dst1[base + i] >> 8], 1);
        atomicAdd(&h[NB + (dst2[base + i] >> 8)], 1);
    }
    __syncthreads();
    for (int i = t; i < 2 * NB; i += 1024)
        histG[(size_t)i * NBLK + blk] = h[i];
}

// ---------------- phase B1: exclusive scan of each gb row across blocks ----------------
__global__ __launch_bounds__(NBLK) void scanB1_kernel(int* __restrict__ histG, int* __restrict__ btot)
{
    __shared__ int s[NBLK];
    const int t = threadIdx.x, row = blockIdx.x;
    int v = histG[(size_t)row * NBLK + t];
    s[t] = v;
    __syncthreads();
    for (int off = 1; off < NBLK; off <<= 1) {
        int x = (t >= off) ? s[t - off] : 0;
        __syncthreads();
        s[t] += x;
        __syncthreads();
    }
    histG[(size_t)row * NBLK + t] = s[t] - v;
    if (t == NBLK - 1) btot[row] = s[t];
}

// ---------------- phase B2: exclusive scan of bucket totals per graph ----------------
__global__ __launch_bounds__(256) void scanB2_kernel(const int* __restrict__ btot, int* __restrict__ bbase)
{
    __shared__ int sc[256];
    const int t = threadIdx.x;
    for (int g = 0; g < 2; g++) {
        int v = (t < NB) ? btot[g * NB + t] : 0;
        sc[t] = v;
        __syncthreads();
        for (int off = 1; off < 256; off <<= 1) {
            int x = (t >= off) ? sc[t - off] : 0;
            __syncthreads();
            sc[t] += x;
            __syncthreads();
        }
        if (t < NB) bbase[g * NB + t] = sc[t] - v;
        __syncthreads();
    }
}

// ---------------- phase C: deterministic scatter into bucket-contiguous bins ----------------
__global__ __launch_bounds__(1024) void scatterC_kernel(
    const int* __restrict__ src1, const int* __restrict__ dst1,
    const int* __restrict__ src2, const int* __restrict__ dst2,
    const int* __restrict__ histG, const int* __restrict__ bbase,
    unsigned int* __restrict__ bin1, unsigned int* __restrict__ bin2)
{
    __shared__ int pos[2 * NB];
    const int t = threadIdx.x, blk = blockIdx.x;
    for (int i = t; i < 2 * NB; i += 1024)
        pos[i] = bbase[i] + histG[(size_t)i * NBLK + blk];
    __syncthreads();
    const int base = blk * CHUNK;
    for (int i = t; i < CHUNK; i += 1024) {
        int d = dst1[base + i], s = src1[base + i];
        int slot = atomicAdd(&pos[d >> 8], 1);
        bin1[slot] = ((unsigned)(d & 255) << 16) | (unsigned)s;
        d = dst2[base + i]; s = src2[base + i];
        slot = atomicAdd(&pos[NB + (d >> 8)], 1);
        bin2[slot] = ((unsigned)(d & 255) << 16) | (unsigned)s;
    }
}

// ---------------- bucket sort: LDS counting sort per bucket, coalesced csr flush ----------------
__global__ __launch_bounds__(256) void bucket_sort_kernel(
    const unsigned int* __restrict__ bin1, const unsigned int* __restrict__ bin2,
    const int* __restrict__ bbase, const int* __restrict__ btot,
    unsigned short* __restrict__ csr1, int* __restrict__ start1, int* __restrict__ deg1,
    unsigned short* __restrict__ csr2, int* __restrict__ start2, int* __restrict__ deg2)
{
    __shared__ int lcnt[256];
    __shared__ int sc[256];
    __shared__ int oat[256];
    __shared__ unsigned short outb[MAXB];
    const int t = threadIdx.x;
    const int g = (blockIdx.x >= NB) ? 1 : 0;
    const int b = blockIdx.x - g * NB;
    const unsigned int* bin = g ? bin2 : bin1;
    unsigned short* csr = g ? csr2 : csr1;
    int* start = g ? start2 : start1;
    int* deg   = g ? deg2 : deg1;

    const int base = bbase[g * NB + b];
    const int tot = min(btot[g * NB + b], MAXB);

    lcnt[t] = 0;
    __syncthreads();
    for (int i = t; i < tot; i += 256) atomicAdd(&lcnt[bin[base + i] >> 16], 1);
    __syncthreads();
    sc[t] = lcnt[t];
    __syncthreads();
    for (int off = 1; off < 256; off <<= 1) {
        int x = (t >= off) ? sc[t - off] : 0;
        __syncthreads();
        sc[t] += x;
        __syncthreads();
    }
    const int ex = sc[t] - lcnt[t];
    oat[t] = ex;
    __syncthreads();
    for (int i = t; i < tot; i += 256) {
        unsigned v = bin[base + i];
        int slot = atomicAdd(&oat[v >> 16], 1);
        outb[slot] = (unsigned short)(v & 0xFFFFu);
    }
    __syncthreads();
    for (int i = t; i < tot; i += 256) csr[base + i] = outb[i];
    int nd = b * 256 + t;
    if (nd < NN) { start[nd] = base + ex; deg[nd] = lcnt[t]; }
}

// ---------------- fused gather + attention: one wave per node, both graphs -------------
// 8-deep software pipeline: all 8 row loads + norms issued before the FMA chain.
__global__ __launch_bounds__(256) void gather_attn_kernel(
    const unsigned int* __restrict__ hfb,
    const unsigned short* __restrict__ csr1, const int* __restrict__ start1,
    const int* __restrict__ deg1, const float* __restrict__ norm1,
    const unsigned short* __restrict__ csr2, const int* __restrict__ start2,
    const int* __restrict__ deg2, const float* __restrict__ norm2,
    const float* __restrict__ al, const float* __restrict__ ar,
    unsigned int* __restrict__ outb)
{
    const int lane = threadIdx.x & 63;
    int node = (blockIdx.x * 256 + threadIdx.x) >> 6;
    if (node >= NN) return;
    node = __builtin_amdgcn_readfirstlane(node);   // wave-uniform -> SGPR

    float2 acc1 = make_float2(0.f, 0.f), acc2 = make_float2(0.f, 0.f);

    #pragma unroll 1
    for (int g = 0; g < 2; g++) {
        const unsigned short* csr = g ? csr2 : csr1;
        const int* startp = g ? start2 : start1;
        const int* degp   = g ? deg2 : deg1;
        const float* norm = g ? norm2 : norm1;
        float2 acc = make_float2(0.f, 0.f);
        const int st = startp[node], dg = degp[node];
        for (int base = 0; base < dg; base += 64) {
            const int nb = min(64, dg - base);
            int myc = (lane < nb) ? (int)csr[st + base + lane] : 0;  // coalesced 128B/wave
            int j = 0;
            for (; j + 8 <= nb; j += 8) {
                int s[8]; float n[8]; unsigned u[8];
                #pragma unroll
                for (int q = 0; q < 8; q++) s[q] = __builtin_amdgcn_readlane(myc, j + q);
                #pragma unroll
                for (int q = 0; q < 8; q++) {
                    n[q] = norm[s[q]];
                    u[q] = hfb[(long)s[q] * 64 + lane];
                }
                #pragma unroll
                for (int q = 0; q < 8; q++) {
                    acc.x = fmaf(bflo(u[q]), n[q], acc.x);
                    acc.y = fmaf(bfhi(u[q]), n[q], acc.y);
                }
            }
            for (; j < nb; j++) {
                int s = __builtin_amdgcn_readlane(myc, j);
                float nv = norm[s];
                unsigned u = hfb[(long)s * 64 + lane];
                acc.x = fmaf(bflo(u), nv, acc.x);
                acc.y = fmaf(bfhi(u), nv, acc.y);
            }
        }
        if (g) acc2 = acc; else acc1 = acc;
    }

    // h1 = acc1*norm1[node], h2 = acc2*norm2[node]
    const float nn1 = norm1[node], nn2 = norm2[node];
    acc1.x *= nn1; acc1.y *= nn1;
    acc2.x *= nn2; acc2.y *= nn2;

    // attention combine in flat-reshape space: lane owns cols {2*lane, 2*lane+1}
    const int cc = lane >> 3;
    const int m = node * 8 + cc;
    const int head = m / NN;
    const int hid = (2 * lane) & 15;
    unsigned uf = hfb[(long)node * 64 + lane];
    const float fx = bflo(uf), fy = bfhi(uf);
    const float av0 = al[head * 16 + hid], av1 = al[head * 16 + hid + 1];
    const float rv0 = ar[head * 16 + hid], rv1 = ar[head * 16 + hid + 1];
    float s_ai = fx * av0 + fy * av1;
    float s1 = acc1.x * rv0 + acc1.y * rv1;
    float s2 = acc2.x * rv0 + acc2.y * rv1;
    s_ai += __shfl_xor(s_ai, 1); s_ai += __shfl_xor(s_ai, 2); s_ai += __shfl_xor(s_ai, 4);
    s1   += __shfl_xor(s1, 1);   s1   += __shfl_xor(s1, 2);   s1   += __shfl_xor(s1, 4);
    s2   += __shfl_xor(s2, 1);   s2   += __shfl_xor(s2, 2);   s2   += __shfl_xor(s2, 4);
    float x1 = s_ai + s1; x1 = x1 > 0.f ? x1 : 0.2f * x1;
    float x2 = s_ai + s2; x2 = x2 > 0.f ? x2 : 0.2f * x2;
    float e1 = fminf(expf(x1), 10.f);
    float e2 = fminf(expf(x2), 10.f);
    float inv = 1.f / (e1 + e2);
    float w1 = e1 * inv, w2 = e2 * inv;
    float ox = w1 * acc1.x + w2 * acc2.x;
    float oy = w1 * acc1.y + w2 * acc2.y;
    outb[(long)node * 64 + lane] = (unsigned)f2bf(ox) | ((unsigned)f2bf(oy) << 16);
}

extern "C" void kernel_launch(void* const* d_in, const int* in_sizes, int n_in,
                              void* d_out, int out_size, void* d_ws, size_t ws_size,
                              hipStream_t stream)
{
    const float* h     = (const float*)d_in[0];
    const int*   src1  = (const int*)  d_in[1];
    const int*   dst1  = (const int*)  d_in[2];
    const int*   src2  = (const int*)  d_in[3];
    const int*   dst2  = (const int*)  d_in[4];
    const float* norm1 = (const float*)d_in[5];
    const float* norm2 = (const float*)d_in[6];
    const float* W_lin = (const float*)d_in[7];
    const float* b_lin = (const float*)d_in[8];
    const float* al    = (const float*)d_in[9];
    const float* ar    = (const float*)d_in[10];
    const float* W_fc  = (const float*)d_in[11];
    const float* b_fc  = (const float*)d_in[12];
    float* out = (float*)d_out;

    // workspace layout
    unsigned short* hfb  = (unsigned short*)d_ws;         // NN*128 bf16 = 12.8 MB
    unsigned short* outbf = hfb + (size_t)NN * 128;       // NN*128 bf16 = 12.8 MB
    unsigned int* bin1 = (unsigned int*)(outbf + (size_t)NN * 128);  // NE u32
    unsigned int* bin2 = bin1 + NE;                       // NE u32
    unsigned short* csr1 = (unsigned short*)(bin2 + NE);  // NE u16
    unsigned short* csr2 = csr1 + NE;                     // NE u16
    unsigned short* WtL  = csr2 + NE;                     // 16384 u16
    unsigned short* WtF  = WtL + 128 * 128;               // 16384 u16
    int* histG  = (int*)(WtF + 128 * 128);                // 2*NB*NBLK ints
    int* btot   = histG + 2 * NB * NBLK;
    int* bbase  = btot + 2 * NB;
    int* start1 = bbase + 2 * NB;
    int* start2 = start1 + NN;
    int* deg1   = start2 + NN;
    int* deg2   = deg1 + NN;

    // pre-convert both weight matrices to bf16 k-major (once)
    convert_w_kernel<<<2, 256, 0, stream>>>(W_lin, W_fc, WtL, WtF);

    // hfb = bf16(h @ W_lin + b_lin)
    mfma_gemm_kernel<<<(NN + 63) / 64, 256, 0, stream>>>(h, WtL, b_lin, nullptr, hfb, NN);

    // deterministic CSR build
    histA_kernel<<<NBLK, 1024, 0, stream>>>(dst1, dst2, histG);
    scanB1_kernel<<<2 * NB, NBLK, 0, stream>>>(histG, btot);
    scanB2_kernel<<<1, 256, 0, stream>>>(btot, bbase);
    scatterC_kernel<<<NBLK, 1024, 0, stream>>>(src1, dst1, src2, dst2, histG, bbase, bin1, bin2);
    bucket_sort_kernel<<<2 * NB, 256, 0, stream>>>(bin1, bin2, bbase, btot,
                                                   csr1, start1, deg1,
                                                   csr2, start2, deg2);

    // fused gather (both graphs) + attention combine -> bf16
    gather_attn_kernel<<<(NN * 64 + 255) / 256, 256, 0, stream>>>(
        (const unsigned int*)hfb,
        csr1, start1, deg1, norm1,
        csr2, start2, deg2, norm2,
        al, ar, (unsigned int*)outbf);

    // out = outbf @ W_fc + b_fc
    mfma_gemm_bf16_kernel<<<(NN + 63) / 64, 256, 0, stream>>>(outbf, WtF, b_fc, out, NN);
}